// Round 1
// baseline (374.872 us; speedup 1.0000x reference)
//
#include <hip/hip_runtime.h>

// Problem: B=4, C=256, N=H*W=4096, GROUPS=16, qkv: 768x256, proj: 256x256.
// Pipeline: gn_stats -> gn_apply(transpose->bf16) -> qkv GEMM (bf16 MFMA)
//           -> flash attention (no-max softmax, KV-split=2) -> combine -> proj GEMM (+residual)

typedef unsigned short u16;
typedef __attribute__((ext_vector_type(8))) short short8;   // 8 x bf16 (4 VGPRs)
typedef __attribute__((ext_vector_type(4))) float f32x4;    // MFMA accumulator

// workspace byte offsets (total ~59.4 MB)
#define XN_OFF   0ull            // xn  [4][4096][256] bf16   (8,388,608 B)
#define QW_OFF   8388608ull      // q   [4][4096][256] bf16 (scaled by log2e/16)
#define KW_OFF   16777216ull     // k   [4][4096][256] bf16
#define VW_OFF   25165824ull     // v^T [4][256][4096] bf16
#define AO_OFF   33554432ull     // ao  [4][4096][256] bf16
#define OP_OFF   41943040ull     // opart [2][4][4096][256] bf16 (16,777,216 B)
#define LP_OFF   58720256ull     // lpart [2][4][4096] f32 (131,072 B)
#define WQB_OFF  58851328ull     // qkv_w bf16 (393,216 B)
#define WPB_OFF  59244544ull     // proj_w bf16 (131,072 B)
#define ST_OFF   59375616ull     // stats [64][2] f32

__device__ __forceinline__ u16 f2bf(float x){
  unsigned u = __float_as_uint(x);
  u += 0x7fffu + ((u >> 16) & 1u);          // RNE
  return (u16)(u >> 16);
}
__device__ __forceinline__ float bf2f(u16 h){
  return __uint_as_float(((unsigned)h) << 16);
}

// ---------------- GroupNorm stats: one block per (b,g), 16ch*4096 = 65536 vals ----------------
__global__ __launch_bounds__(256) void gn_stats_k(const float* __restrict__ x, float* __restrict__ stats){
  int bg = blockIdx.x;                       // b*16+g
  const float* base = x + (size_t)bg * 65536;
  float s = 0.f, ss = 0.f;
  for (int i = threadIdx.x; i < 16384; i += 256){
    float4 v = ((const float4*)base)[i];
    s  += (v.x + v.y) + (v.z + v.w);
    ss += (v.x*v.x + v.y*v.y) + (v.z*v.z + v.w*v.w);
  }
  for (int off = 32; off; off >>= 1){ s += __shfl_down(s, off, 64); ss += __shfl_down(ss, off, 64); }
  __shared__ float red[8];
  int wave = threadIdx.x >> 6, lane = threadIdx.x & 63;
  if (lane == 0){ red[wave] = s; red[4 + wave] = ss; }
  __syncthreads();
  if (threadIdx.x == 0){
    float S  = red[0] + red[1] + red[2] + red[3];
    float SS = red[4] + red[5] + red[6] + red[7];
    float mu = S * (1.f/65536.f);
    float var = SS * (1.f/65536.f) - mu*mu;
    stats[bg*2]   = mu;
    stats[bg*2+1] = rsqrtf(var + 1e-5f);
  }
}

// ---------------- GN apply + transpose: x[b][c][n] f32 -> xn[b][n][c] bf16 ----------------
__global__ __launch_bounds__(256) void gn_apply_k(const float* __restrict__ x, const float* __restrict__ gw,
                                                  const float* __restrict__ gb, const float* __restrict__ stats,
                                                  u16* __restrict__ xn){
  int b = blockIdx.z, c0 = blockIdx.y*64, n0 = blockIdx.x*64;
  __shared__ float tile[64*65];
  int t = threadIdx.x;
  for (int i = 0; i < 16; ++i){
    int idx = i*256 + t;
    int cl = idx >> 6, nl = idx & 63;
    int c = c0 + cl;
    float mu = stats[(b*16 + (c>>4))*2];
    float rs = stats[(b*16 + (c>>4))*2 + 1];
    float v = x[((size_t)b*256 + c)*4096 + n0 + nl];
    tile[cl*65 + nl] = (v - mu)*rs*gw[c] + gb[c];
  }
  __syncthreads();
  for (int i = 0; i < 16; ++i){
    int idx = i*256 + t;
    int nl = idx >> 6, cl = idx & 63;
    xn[((size_t)b*4096 + n0 + nl)*256 + c0 + cl] = f2bf(tile[cl*65 + nl]);
  }
}

// ---------------- weight f32 -> bf16 ----------------
__global__ __launch_bounds__(256) void wcvt_k(const float* __restrict__ wq, const float* __restrict__ wp,
                                              u16* __restrict__ wqb, u16* __restrict__ wpb){
  int i = blockIdx.x*256 + threadIdx.x;
  if (i < 196608) wqb[i] = f2bf(wq[i]);
  else            wpb[i - 196608] = f2bf(wp[i - 196608]);
}

// ---------------- qkv GEMM: C[m=pixel][o] = sum_c xn[m][c]*W[o][c]; 128x128 tile ----------------
#define LDA 40   // padded LDS row stride (u16) for 32-wide k-tile: 2-way max bank alias
#define QSCALE 0.09016844f   // log2(e)/16
__global__ __launch_bounds__(256) void qkv_gemm_k(const u16* __restrict__ xn, const u16* __restrict__ wq,
        const float* __restrict__ qb, u16* __restrict__ q, u16* __restrict__ k, u16* __restrict__ v){
  int bx = blockIdx.x;           // o-tile 0..5 (0-1:q, 2-3:k, 4-5:v)
  int m0 = blockIdx.y*128;       // pixel tile
  int b  = blockIdx.z;
  __shared__ u16 smem[16384];    // 32 KB: A(5120)+B(5120); v-transpose reuses all 32KB
  u16* As = smem;
  u16* Bs = smem + 5120;
  int t = threadIdx.x, lane = t & 63, wave = t >> 6;
  int wm = wave >> 1, wn = wave & 1;
  int c15 = lane & 15, g = lane >> 4;
  f32x4 acc[4][4];
  for (int mt = 0; mt < 4; ++mt) for (int nt = 0; nt < 4; ++nt) acc[mt][nt] = (f32x4){0.f,0.f,0.f,0.f};
  const u16* abase = xn + ((size_t)b*4096 + m0)*256;
  const u16* bbase = wq + (size_t)bx*128*256;
  for (int kk = 0; kk < 8; ++kk){
    int k0 = kk*32;
    for (int it = 0; it < 2; ++it){
      int idx = it*256 + t;               // 0..511 -> 128 rows x 4 chunks
      int row = idx >> 2, ch = idx & 3;
      uint4 va = *(const uint4*)(abase + (size_t)row*256 + k0 + ch*8);
      *(uint4*)(As + row*LDA + ch*8) = va;
      uint4 vb = *(const uint4*)(bbase + (size_t)row*256 + k0 + ch*8);
      *(uint4*)(Bs + row*LDA + ch*8) = vb;
    }
    __syncthreads();
    short8 af[4], bfr[4];
    for (int mt = 0; mt < 4; ++mt) af[mt]  = *(const short8*)(As + (wm*64 + mt*16 + c15)*LDA + g*8);
    for (int nt = 0; nt < 4; ++nt) bfr[nt] = *(const short8*)(Bs + (wn*64 + nt*16 + c15)*LDA + g*8);
    for (int mt = 0; mt < 4; ++mt)
      for (int nt = 0; nt < 4; ++nt)
        acc[mt][nt] = __builtin_amdgcn_mfma_f32_16x16x32_bf16(af[mt], bfr[nt], acc[mt][nt], 0, 0, 0);
    __syncthreads();
  }
  if (bx < 4){
    u16* dst = (bx < 2) ? q : k;
    int csub = (bx < 2) ? 0 : 256;
    for (int nt = 0; nt < 4; ++nt){
      int col = bx*128 + wn*64 + nt*16 + c15;
      float bias = qb[col];
      for (int mt = 0; mt < 4; ++mt){
        int m = m0 + wm*64 + mt*16 + g*4;
        for (int r = 0; r < 4; ++r){
          float val = acc[mt][nt][r] + bias;
          if (bx < 2) val *= QSCALE;      // fold softmax scale+log2e into q
          dst[((size_t)b*4096 + m + r)*256 + (col - csub)] = f2bf(val);
        }
      }
    }
  } else {
    // v: transpose 128x128 tile through swizzled LDS -> v^T[b][c][n] coalesced stores
    __syncthreads();
    char* Tb = (char*)smem;
    for (int nt = 0; nt < 4; ++nt){
      int o_l = wn*64 + nt*16 + c15;            // 0..127 (channel within tile)
      float bias = qb[bx*128 + o_l];
      for (int mt = 0; mt < 4; ++mt){
        int mb = wm*64 + mt*16 + g*4;           // pixel base (multiple of 4)
        unsigned p0 = (unsigned)f2bf(acc[mt][nt][0] + bias) | ((unsigned)f2bf(acc[mt][nt][1] + bias) << 16);
        unsigned p1 = (unsigned)f2bf(acc[mt][nt][2] + bias) | ((unsigned)f2bf(acc[mt][nt][3] + bias) << 16);
        int base = o_l*256 + (((mb >> 3) ^ (o_l & 7)) << 4) + ((mb & 7) << 1);
        *(unsigned*)(Tb + base)     = p0;
        *(unsigned*)(Tb + base + 4) = p1;
      }
    }
    __syncthreads();
    for (int it = 0; it < 8; ++it){
      int idx = it*256 + t;                     // 0..2047 -> 128 rows x 16 chunks
      int ro = idx >> 4, ch = idx & 15;
      uint4 val = *(const uint4*)(Tb + ro*256 + ((ch ^ (ro & 7)) << 4));
      int c = bx*128 - 512 + ro;
      *(uint4*)(v + ((size_t)b*256 + c)*4096 + m0 + ch*8) = val;
    }
  }
}

// ---------------- flash attention, no-max softmax, Br=64, Bc=64, KV-split=2 ----------------
__global__ __launch_bounds__(256) void flash_k(const u16* __restrict__ q, const u16* __restrict__ k,
                                               const u16* __restrict__ v, u16* __restrict__ opart,
                                               float* __restrict__ lpart){
  int n0 = blockIdx.x*64;
  int jh = blockIdx.y;           // kv half
  int b  = blockIdx.z;
  __shared__ u16 klds[64*256];   // 32 KB, xor-swizzled 16B chunks
  __shared__ u16 vlds[256*64];   // 32 KB, v^T tile, xor-swizzled
  int t = threadIdx.x, lane = t & 63, wave = t >> 6;
  int c15 = lane & 15, g = lane >> 4;

  // Q B-frags, resident in registers: Q[i=c15][kb*32 + g*8 .. +7]
  uint4 qf[8];
  const u16* qrow = q + ((size_t)b*4096 + n0 + wave*16 + c15)*256;
  for (int kb = 0; kb < 8; ++kb) qf[kb] = *(const uint4*)(qrow + kb*32 + g*8);

  f32x4 oacc[16];
  for (int ct = 0; ct < 16; ++ct) oacc[ct] = (f32x4){0.f,0.f,0.f,0.f};
  float lsum = 0.f;

  const uint4* ksrc0 = (const uint4*)(k + ((size_t)b*4096 + jh*2048)*256);
  const u16*   vbase = v + (size_t)b*256*4096 + jh*2048;

  for (int jt = 0; jt < 32; ++jt){
    // stage K tile (64 rows x 512B, contiguous) and V^T tile (256 rows x 128B)
    const uint4* ks = ksrc0 + (size_t)jt*2048;
    for (int it = 0; it < 8; ++it){
      int idx = it*256 + t;
      int row = idx >> 5, ch = idx & 31;
      uint4 kv4 = ks[idx];
      *(uint4*)(klds + row*256 + ((ch ^ (row & 7)) << 3)) = kv4;
      int vc = it*32 + (t >> 3), vch = t & 7;
      uint4 vv4 = *(const uint4*)(vbase + (size_t)vc*4096 + jt*64 + vch*8);
      *(uint4*)(vlds + vc*64 + ((vch ^ (vc & 7)) << 3)) = vv4;
    }
    __syncthreads();

    // S^T = K * Q^T : lane holds S^T[j=16*tt+4g+r][i=c15]
    f32x4 sacc[4];
    for (int tt = 0; tt < 4; ++tt) sacc[tt] = (f32x4){0.f,0.f,0.f,0.f};
    for (int kb = 0; kb < 8; ++kb){
      short8 qfr = *(const short8*)&qf[kb];
      for (int tt = 0; tt < 4; ++tt){
        int j = tt*16 + c15;
        short8 kf = *(const short8*)(klds + j*256 + (((kb*4 + g) ^ (j & 7)) << 3));
        sacc[tt] = __builtin_amdgcn_mfma_f32_16x16x32_bf16(kf, qfr, sacc[tt], 0, 0, 0);
      }
    }
    // no-max softmax numerator (scores pre-scaled to log2-domain), partial row-sum
    unsigned pkv[8];
    for (int tt = 0; tt < 4; ++tt){
      float p0 = exp2f(sacc[tt][0]);
      float p1 = exp2f(sacc[tt][1]);
      float p2 = exp2f(sacc[tt][2]);
      float p3 = exp2f(sacc[tt][3]);
      lsum += (p0 + p1) + (p2 + p3);
      pkv[tt*2]   = (unsigned)f2bf(p0) | ((unsigned)f2bf(p1) << 16);
      pkv[tt*2+1] = (unsigned)f2bf(p2) | ((unsigned)f2bf(p3) << 16);
    }
    // butterfly: C-layout P^T -> A-operand frags P[i=c15][j], then O += P*V
    for (int tp = 0; tp < 2; ++tp){
      uint4 fr;
      unsigned* frp = (unsigned*)&fr;
      for (int qd = 0; qd < 4; ++qd){
        int src = c15 + 16*(2*(g & 1) + (qd >> 1));
        unsigned a   = (unsigned)__shfl((int)pkv[4*tp + (qd & 1)],     src, 64);
        unsigned bsh = (unsigned)__shfl((int)pkv[4*tp + 2 + (qd & 1)], src, 64);
        frp[qd] = (g >> 1) ? bsh : a;
      }
      short8 pfr = *(const short8*)&fr;
      for (int ct = 0; ct < 16; ++ct){
        int c = ct*16 + c15;
        short8 vf = *(const short8*)(vlds + c*64 + (((tp*4 + g) ^ (c & 7)) << 3));
        oacc[ct] = __builtin_amdgcn_mfma_f32_16x16x32_bf16(pfr, vf, oacc[ct], 0, 0, 0);
      }
    }
    __syncthreads();
  }

  // epilogue: reduce l across the 4 lane-groups of each row, store partials
  float tot = lsum;
  tot += __shfl_xor(tot, 16, 64);
  tot += __shfl_xor(tot, 32, 64);
  if (g == 0) lpart[(size_t)(jh*4 + b)*4096 + n0 + wave*16 + c15] = tot;
  u16* obase = opart + ((size_t)(jh*4 + b)*4096 + n0 + wave*16)*256;
  for (int ct = 0; ct < 16; ++ct)
    for (int r = 0; r < 4; ++r)
      obase[(size_t)(g*4 + r)*256 + ct*16 + c15] = f2bf(oacc[ct][r]);
}

// ---------------- combine KV-split partials -> ao[b][n][c] bf16 ----------------
__global__ __launch_bounds__(256) void combine_k(const u16* __restrict__ opart, const float* __restrict__ lpart,
                                                 u16* __restrict__ ao){
  size_t e8 = (size_t)blockIdx.x*256 + threadIdx.x;   // 8-elem chunk index, 524288 total
  size_t row = e8 >> 5;                               // b*4096+n
  uint4 o0 = *(const uint4*)(opart + e8*8);
  uint4 o1 = *(const uint4*)(opart + 4194304ull + e8*8);
  float inv = 1.0f / (lpart[row] + lpart[16384 + row]);
  const unsigned* u0 = (const unsigned*)&o0;
  const unsigned* u1 = (const unsigned*)&o1;
  uint4 w;
  unsigned* wp = (unsigned*)&w;
  for (int i = 0; i < 4; ++i){
    float lo = (bf2f((u16)(u0[i] & 0xffff)) + bf2f((u16)(u1[i] & 0xffff))) * inv;
    float hi = (bf2f((u16)(u0[i] >> 16))    + bf2f((u16)(u1[i] >> 16)))    * inv;
    wp[i] = (unsigned)f2bf(lo) | ((unsigned)f2bf(hi) << 16);
  }
  *(uint4*)(ao + e8*8) = w;
}

// ---------------- proj GEMM + bias + residual: out[b][o][n] = x + W*ao + b ----------------
__global__ __launch_bounds__(256) void proj_gemm_k(const u16* __restrict__ ao, const u16* __restrict__ wp,
        const float* __restrict__ pb, const float* __restrict__ x, float* __restrict__ out){
  int n0 = blockIdx.x*128;       // pixel tile
  int m0 = blockIdx.y*128;       // channel tile (0 or 128)
  int b  = blockIdx.z;
  __shared__ u16 smem[10240];
  u16* As = smem;                // proj_w rows [128][LDA]
  u16* Bs = smem + 5120;         // ao rows    [128][LDA]
  int t = threadIdx.x, lane = t & 63, wave = t >> 6;
  int wm = wave >> 1, wn = wave & 1;
  int c15 = lane & 15, g = lane >> 4;
  f32x4 acc[4][4];
  for (int mt = 0; mt < 4; ++mt) for (int nt = 0; nt < 4; ++nt) acc[mt][nt] = (f32x4){0.f,0.f,0.f,0.f};
  const u16* abase = wp + (size_t)m0*256;
  const u16* bbase = ao + ((size_t)b*4096 + n0)*256;
  for (int kk = 0; kk < 8; ++kk){
    int k0 = kk*32;
    for (int it = 0; it < 2; ++it){
      int idx = it*256 + t;
      int row = idx >> 2, ch = idx & 3;
      uint4 va = *(const uint4*)(abase + (size_t)row*256 + k0 + ch*8);
      *(uint4*)(As + row*LDA + ch*8) = va;
      uint4 vb = *(const uint4*)(bbase + (size_t)row*256 + k0 + ch*8);
      *(uint4*)(Bs + row*LDA + ch*8) = vb;
    }
    __syncthreads();
    short8 af[4], bfr[4];
    for (int mt = 0; mt < 4; ++mt) af[mt]  = *(const short8*)(As + (wm*64 + mt*16 + c15)*LDA + g*8);
    for (int nt = 0; nt < 4; ++nt) bfr[nt] = *(const short8*)(Bs + (wn*64 + nt*16 + c15)*LDA + g*8);
    for (int mt = 0; mt < 4; ++mt)
      for (int nt = 0; nt < 4; ++nt)
        acc[mt][nt] = __builtin_amdgcn_mfma_f32_16x16x32_bf16(af[mt], bfr[nt], acc[mt][nt], 0, 0, 0);
    __syncthreads();
  }
  for (int mt = 0; mt < 4; ++mt){
    for (int r = 0; r < 4; ++r){
      int o = m0 + wm*64 + mt*16 + g*4 + r;
      float bias = pb[o];
      for (int nt = 0; nt < 4; ++nt){
        int n = n0 + wn*64 + nt*16 + c15;
        size_t off = ((size_t)b*256 + o)*4096 + n;
        out[off] = x[off] + bias + acc[mt][nt][r];
      }
    }
  }
}

extern "C" void kernel_launch(void* const* d_in, const int* in_sizes, int n_in,
                              void* d_out, int out_size, void* d_ws, size_t ws_size,
                              hipStream_t stream){
  (void)in_sizes; (void)n_in; (void)out_size; (void)ws_size;
  const float* x     = (const float*)d_in[0];
  const float* gw    = (const float*)d_in[1];
  const float* gb    = (const float*)d_in[2];
  const float* qkvw  = (const float*)d_in[3];
  const float* qkvb  = (const float*)d_in[4];
  const float* projw = (const float*)d_in[5];
  const float* projb = (const float*)d_in[6];
  float* out = (float*)d_out;
  char* ws = (char*)d_ws;

  u16*   xn    = (u16*)(ws + XN_OFF);
  u16*   qws   = (u16*)(ws + QW_OFF);
  u16*   kws   = (u16*)(ws + KW_OFF);
  u16*   vws   = (u16*)(ws + VW_OFF);
  u16*   ao    = (u16*)(ws + AO_OFF);
  u16*   op    = (u16*)(ws + OP_OFF);
  float* lp    = (float*)(ws + LP_OFF);
  u16*   wqb   = (u16*)(ws + WQB_OFF);
  u16*   wpb   = (u16*)(ws + WPB_OFF);
  float* stats = (float*)(ws + ST_OFF);

  wcvt_k<<<1024, 256, 0, stream>>>(qkvw, projw, wqb, wpb);
  gn_stats_k<<<64, 256, 0, stream>>>(x, stats);
  gn_apply_k<<<dim3(64, 4, 4), 256, 0, stream>>>(x, gw, gb, stats, xn);
  qkv_gemm_k<<<dim3(6, 32, 4), 256, 0, stream>>>(xn, wqb, qkvb, qws, kws, vws);
  flash_k<<<dim3(64, 2, 4), 256, 0, stream>>>(qws, kws, vws, op, lp);
  combine_k<<<2048, 256, 0, stream>>>(op, lp, ao);
  proj_gemm_k<<<dim3(32, 2, 4), 256, 0, stream>>>(ao, wpb, projb, x, out);
}

// Round 3
// 304.578 us; speedup vs baseline: 1.2308x; 1.2308x over previous
//
#include <hip/hip_runtime.h>

// Problem: B=4, C=256, N=H*W=4096, GROUPS=16, qkv: 768x256, proj: 256x256.
// Pipeline: gn_stats -> gn_apply(transpose->bf16) -> qkv GEMM (bf16 MFMA)
//           -> flash attention (no-max softmax, KV-split=4, 32 q-rows/wave) -> combine -> proj GEMM (+residual)

typedef unsigned short u16;
typedef __attribute__((ext_vector_type(8))) short short8;   // 8 x bf16 (4 VGPRs)
typedef __attribute__((ext_vector_type(4))) float f32x4;    // MFMA accumulator

// workspace byte offsets (total ~59.5 MB)
// opart [4 splits][4 b][4096][256] bf16 overlays xn (xn dead after qkv GEMM);
// ao aliases opart split 0 (combine reads all splits before writing its slot).
#define XN_OFF   0ull            // xn  [4][4096][256] bf16 (8,388,608 B)
#define OP_OFF   0ull            // opart [4][4][4096][256] bf16 (33,554,432 B)
#define QW_OFF   33554432ull     // q   [4][4096][256] bf16 (scaled by log2e/16)
#define KW_OFF   41943040ull     // k   [4][4096][256] bf16
#define VW_OFF   50331648ull     // v^T [4][256][4096] bf16
#define LP_OFF   58720256ull     // lpart [4][4][4096] f32 (262,144 B)
#define WQB_OFF  58982400ull     // qkv_w bf16 (393,216 B)
#define WPB_OFF  59375616ull     // proj_w bf16 (131,072 B)
#define ST_OFF   59506688ull     // stats [64][2] f32

__device__ __forceinline__ u16 f2bf(float x){
  unsigned u = __float_as_uint(x);
  u += 0x7fffu + ((u >> 16) & 1u);          // RNE
  return (u16)(u >> 16);
}
__device__ __forceinline__ float bf2f(u16 h){
  return __uint_as_float(((unsigned)h) << 16);
}

// ---------------- GroupNorm stats: one block per (b,g), 16ch*4096 = 65536 vals ----------------
__global__ __launch_bounds__(256) void gn_stats_k(const float* __restrict__ x, float* __restrict__ stats){
  int bg = blockIdx.x;                       // b*16+g
  const float* base = x + (size_t)bg * 65536;
  float s = 0.f, ss = 0.f;
  for (int i = threadIdx.x; i < 16384; i += 256){
    float4 v = ((const float4*)base)[i];
    s  += (v.x + v.y) + (v.z + v.w);
    ss += (v.x*v.x + v.y*v.y) + (v.z*v.z + v.w*v.w);
  }
  for (int off = 32; off; off >>= 1){ s += __shfl_down(s, off, 64); ss += __shfl_down(ss, off, 64); }
  __shared__ float red[8];
  int wave = threadIdx.x >> 6, lane = threadIdx.x & 63;
  if (lane == 0){ red[wave] = s; red[4 + wave] = ss; }
  __syncthreads();
  if (threadIdx.x == 0){
    float S  = red[0] + red[1] + red[2] + red[3];
    float SS = red[4] + red[5] + red[6] + red[7];
    float mu = S * (1.f/65536.f);
    float var = SS * (1.f/65536.f) - mu*mu;
    stats[bg*2]   = mu;
    stats[bg*2+1] = rsqrtf(var + 1e-5f);
  }
}

// ---------------- GN apply + transpose: x[b][c][n] f32 -> xn[b][n][c] bf16 ----------------
__global__ __launch_bounds__(256) void gn_apply_k(const float* __restrict__ x, const float* __restrict__ gw,
                                                  const float* __restrict__ gb, const float* __restrict__ stats,
                                                  u16* __restrict__ xn){
  int b = blockIdx.z, c0 = blockIdx.y*64, n0 = blockIdx.x*64;
  __shared__ float tile[64*65];
  int t = threadIdx.x;
  for (int i = 0; i < 16; ++i){
    int idx = i*256 + t;
    int cl = idx >> 6, nl = idx & 63;
    int c = c0 + cl;
    float mu = stats[(b*16 + (c>>4))*2];
    float rs = stats[(b*16 + (c>>4))*2 + 1];
    float v = x[((size_t)b*256 + c)*4096 + n0 + nl];
    tile[cl*65 + nl] = (v - mu)*rs*gw[c] + gb[c];
  }
  __syncthreads();
  for (int i = 0; i < 16; ++i){
    int idx = i*256 + t;
    int nl = idx >> 6, cl = idx & 63;
    xn[((size_t)b*4096 + n0 + nl)*256 + c0 + cl] = f2bf(tile[cl*65 + nl]);
  }
}

// ---------------- weight f32 -> bf16 ----------------
__global__ __launch_bounds__(256) void wcvt_k(const float* __restrict__ wq, const float* __restrict__ wp,
                                              u16* __restrict__ wqb, u16* __restrict__ wpb){
  int i = blockIdx.x*256 + threadIdx.x;
  if (i < 196608) wqb[i] = f2bf(wq[i]);
  else            wpb[i - 196608] = f2bf(wp[i - 196608]);
}

// ---------------- qkv GEMM: C[m=pixel][o] = sum_c xn[m][c]*W[o][c]; 128x128 tile ----------------
#define LDA 40   // padded LDS row stride (u16) for 32-wide k-tile
#define QSCALE 0.09016844f   // log2(e)/16
__global__ __launch_bounds__(256) void qkv_gemm_k(const u16* __restrict__ xn, const u16* __restrict__ wq,
        const float* __restrict__ qb, u16* __restrict__ q, u16* __restrict__ k, u16* __restrict__ v){
  int bx = blockIdx.x;           // o-tile 0..5 (0-1:q, 2-3:k, 4-5:v)
  int m0 = blockIdx.y*128;       // pixel tile
  int b  = blockIdx.z;
  __shared__ u16 smem[16384];    // 32 KB: A(5120)+B(5120); v-transpose reuses all 32KB
  u16* As = smem;
  u16* Bs = smem + 5120;
  int t = threadIdx.x, lane = t & 63, wave = t >> 6;
  int wm = wave >> 1, wn = wave & 1;
  int c15 = lane & 15, g = lane >> 4;
  f32x4 acc[4][4];
  for (int mt = 0; mt < 4; ++mt) for (int nt = 0; nt < 4; ++nt) acc[mt][nt] = (f32x4){0.f,0.f,0.f,0.f};
  const u16* abase = xn + ((size_t)b*4096 + m0)*256;
  const u16* bbase = wq + (size_t)bx*128*256;
  for (int kk = 0; kk < 8; ++kk){
    int k0 = kk*32;
    for (int it = 0; it < 2; ++it){
      int idx = it*256 + t;               // 0..511 -> 128 rows x 4 chunks
      int row = idx >> 2, ch = idx & 3;
      uint4 va = *(const uint4*)(abase + (size_t)row*256 + k0 + ch*8);
      *(uint4*)(As + row*LDA + ch*8) = va;
      uint4 vb = *(const uint4*)(bbase + (size_t)row*256 + k0 + ch*8);
      *(uint4*)(Bs + row*LDA + ch*8) = vb;
    }
    __syncthreads();
    short8 af[4], bfr[4];
    for (int mt = 0; mt < 4; ++mt) af[mt]  = *(const short8*)(As + (wm*64 + mt*16 + c15)*LDA + g*8);
    for (int nt = 0; nt < 4; ++nt) bfr[nt] = *(const short8*)(Bs + (wn*64 + nt*16 + c15)*LDA + g*8);
    for (int mt = 0; mt < 4; ++mt)
      for (int nt = 0; nt < 4; ++nt)
        acc[mt][nt] = __builtin_amdgcn_mfma_f32_16x16x32_bf16(af[mt], bfr[nt], acc[mt][nt], 0, 0, 0);
    __syncthreads();
  }
  if (bx < 4){
    u16* dst = (bx < 2) ? q : k;
    int csub = (bx < 2) ? 0 : 256;
    for (int nt = 0; nt < 4; ++nt){
      int col = bx*128 + wn*64 + nt*16 + c15;
      float bias = qb[col];
      for (int mt = 0; mt < 4; ++mt){
        int m = m0 + wm*64 + mt*16 + g*4;
        for (int r = 0; r < 4; ++r){
          float val = acc[mt][nt][r] + bias;
          if (bx < 2) val *= QSCALE;      // fold softmax scale+log2e into q
          dst[((size_t)b*4096 + m + r)*256 + (col - csub)] = f2bf(val);
        }
      }
    }
  } else {
    // v: transpose 128x128 tile through swizzled LDS -> v^T[b][c][n] coalesced stores
    __syncthreads();
    char* Tb = (char*)smem;
    for (int nt = 0; nt < 4; ++nt){
      int o_l = wn*64 + nt*16 + c15;            // 0..127 (channel within tile)
      float bias = qb[bx*128 + o_l];
      for (int mt = 0; mt < 4; ++mt){
        int mb = wm*64 + mt*16 + g*4;           // pixel base (multiple of 4)
        unsigned p0 = (unsigned)f2bf(acc[mt][nt][0] + bias) | ((unsigned)f2bf(acc[mt][nt][1] + bias) << 16);
        unsigned p1 = (unsigned)f2bf(acc[mt][nt][2] + bias) | ((unsigned)f2bf(acc[mt][nt][3] + bias) << 16);
        int base = o_l*256 + (((mb >> 3) ^ (o_l & 7)) << 4) + ((mb & 7) << 1);
        *(unsigned*)(Tb + base)     = p0;
        *(unsigned*)(Tb + base + 4) = p1;
      }
    }
    __syncthreads();
    for (int it = 0; it < 8; ++it){
      int idx = it*256 + t;                     // 0..2047 -> 128 rows x 16 chunks
      int ro = idx >> 4, ch = idx & 15;
      uint4 val = *(const uint4*)(Tb + ro*256 + ((ch ^ (ro & 7)) << 4));
      int c = bx*128 - 512 + ro;
      *(uint4*)(v + ((size_t)b*256 + c)*4096 + m0 + ch*8) = val;
    }
  }
}

// ---------------- flash attention: no-max softmax, Br=128 (4 waves x 32 rows), Bc=64, KV-split=4 ----------------
__global__ __launch_bounds__(256, 2) void flash_k(const u16* __restrict__ q, const u16* __restrict__ k,
                                                  const u16* __restrict__ v, u16* __restrict__ opart,
                                                  float* __restrict__ lpart){
  int n0 = blockIdx.x*128;
  int jh = blockIdx.y;           // kv quarter: j in [jh*1024, jh*1024+1024)
  int b  = blockIdx.z;
  __shared__ u16 klds[64*256];   // 32 KB, xor-swizzled 16B chunks
  __shared__ u16 vlds[256*64];   // 32 KB, v^T tile, xor-swizzled
  int t = threadIdx.x, lane = t & 63, wave = t >> 6;
  int c15 = lane & 15, g = lane >> 4;

  // Q B-frags for two 16-row i-tiles, resident in registers
  uint4 qf[2][8];
  for (int it2 = 0; it2 < 2; ++it2){
    const u16* qrow = q + ((size_t)b*4096 + n0 + wave*32 + it2*16 + c15)*256;
    for (int kb = 0; kb < 8; ++kb) qf[it2][kb] = *(const uint4*)(qrow + kb*32 + g*8);
  }

  f32x4 oacc[2][16];
  for (int it2 = 0; it2 < 2; ++it2)
    for (int ct = 0; ct < 16; ++ct) oacc[it2][ct] = (f32x4){0.f,0.f,0.f,0.f};
  float lsum[2] = {0.f, 0.f};

  const uint4* ksrc0 = (const uint4*)(k + ((size_t)b*4096 + jh*1024)*256);
  const u16*   vbase = v + (size_t)b*256*4096 + jh*1024;

  for (int jt = 0; jt < 16; ++jt){
    // stage K tile (64 rows x 512B contiguous = 2048 uint4) and V^T tile (256 rows x 128B)
    const uint4* ks = ksrc0 + (size_t)jt*2048;
    for (int it = 0; it < 8; ++it){
      int idx = it*256 + t;
      int row = idx >> 5, ch = idx & 31;
      uint4 kv4 = ks[idx];
      *(uint4*)(klds + row*256 + ((ch ^ (row & 7)) << 3)) = kv4;
      int vc = it*32 + (t >> 3), vch = t & 7;
      uint4 vv4 = *(const uint4*)(vbase + (size_t)vc*4096 + jt*64 + vch*8);
      *(uint4*)(vlds + vc*64 + ((vch ^ (vc & 7)) << 3)) = vv4;
    }
    __syncthreads();

    // S^T = K * Q^T : lane holds S^T[j=16*tt+4g+r][i=c15] for each i-tile
    f32x4 sacc[2][4];
    for (int it2 = 0; it2 < 2; ++it2)
      for (int tt = 0; tt < 4; ++tt) sacc[it2][tt] = (f32x4){0.f,0.f,0.f,0.f};
    for (int kb = 0; kb < 8; ++kb){
      for (int tt = 0; tt < 4; ++tt){
        int j = tt*16 + c15;
        short8 kf = *(const short8*)(klds + j*256 + (((kb*4 + g) ^ (j & 7)) << 3));
        for (int it2 = 0; it2 < 2; ++it2)
          sacc[it2][tt] = __builtin_amdgcn_mfma_f32_16x16x32_bf16(kf, *(const short8*)&qf[it2][kb],
                                                                  sacc[it2][tt], 0, 0, 0);
      }
    }
    // no-max softmax numerator (scores pre-scaled to log2-domain), partial row-sums
    uint4 pfr[2][2];
    for (int it2 = 0; it2 < 2; ++it2){
      unsigned pkv[8];
      for (int tt = 0; tt < 4; ++tt){
        float p0 = exp2f(sacc[it2][tt][0]);
        float p1 = exp2f(sacc[it2][tt][1]);
        float p2 = exp2f(sacc[it2][tt][2]);
        float p3 = exp2f(sacc[it2][tt][3]);
        lsum[it2] += (p0 + p1) + (p2 + p3);
        pkv[tt*2]   = (unsigned)f2bf(p0) | ((unsigned)f2bf(p1) << 16);
        pkv[tt*2+1] = (unsigned)f2bf(p2) | ((unsigned)f2bf(p3) << 16);
      }
      // butterfly: C-layout P^T -> A-operand frags P[i=c15][j]
      for (int tp = 0; tp < 2; ++tp){
        uint4 fr;
        unsigned* frp = (unsigned*)&fr;
        for (int qd = 0; qd < 4; ++qd){
          int src = c15 + 16*(2*(g & 1) + (qd >> 1));
          unsigned a   = (unsigned)__shfl((int)pkv[4*tp + (qd & 1)],     src, 64);
          unsigned bsh = (unsigned)__shfl((int)pkv[4*tp + 2 + (qd & 1)], src, 64);
          frp[qd] = (g >> 1) ? bsh : a;
        }
        pfr[it2][tp] = fr;
      }
    }
    // O += P*V  (V-frag reused across both i-tiles)
    for (int tp = 0; tp < 2; ++tp){
      for (int ct = 0; ct < 16; ++ct){
        int c = ct*16 + c15;
        short8 vf = *(const short8*)(vlds + c*64 + (((tp*4 + g) ^ (c & 7)) << 3));
        for (int it2 = 0; it2 < 2; ++it2)
          oacc[it2][ct] = __builtin_amdgcn_mfma_f32_16x16x32_bf16(*(const short8*)&pfr[it2][tp], vf,
                                                                  oacc[it2][ct], 0, 0, 0);
      }
    }
    __syncthreads();
  }

  // epilogue: reduce l across the 4 lane-groups of each row, store partials
  for (int it2 = 0; it2 < 2; ++it2){
    float tot = lsum[it2];
    tot += __shfl_xor(tot, 16, 64);
    tot += __shfl_xor(tot, 32, 64);
    int row = n0 + wave*32 + it2*16;
    if (g == 0) lpart[(size_t)(jh*4 + b)*4096 + row + c15] = tot;
    u16* obase = opart + ((size_t)(jh*4 + b)*4096 + row)*256;
    for (int ct = 0; ct < 16; ++ct)
      for (int r = 0; r < 4; ++r)
        obase[(size_t)(g*4 + r)*256 + ct*16 + c15] = f2bf(oacc[it2][ct][r]);
  }
}

// ---------------- combine KV-split partials -> ao[b][n][c] bf16 (ao aliases opart split 0) ----------------
__global__ __launch_bounds__(256) void combine_k(const u16* __restrict__ opart, const float* __restrict__ lpart,
                                                 u16* __restrict__ ao){
  size_t e8 = (size_t)blockIdx.x*256 + threadIdx.x;   // 8-elem chunk index, 524288 total
  size_t row = e8 >> 5;                               // b*4096+n
  uint4 o0 = *(const uint4*)(opart + e8*8);
  uint4 o1 = *(const uint4*)(opart + 4194304ull  + e8*8);
  uint4 o2 = *(const uint4*)(opart + 8388608ull  + e8*8);
  uint4 o3 = *(const uint4*)(opart + 12582912ull + e8*8);
  float inv = 1.0f / (lpart[row] + lpart[16384 + row] + lpart[32768 + row] + lpart[49152 + row]);
  const unsigned* u0 = (const unsigned*)&o0;
  const unsigned* u1 = (const unsigned*)&o1;
  const unsigned* u2 = (const unsigned*)&o2;
  const unsigned* u3 = (const unsigned*)&o3;
  uint4 w;
  unsigned* wp = (unsigned*)&w;
  for (int i = 0; i < 4; ++i){
    float lo = (bf2f((u16)(u0[i] & 0xffff)) + bf2f((u16)(u1[i] & 0xffff)) +
                bf2f((u16)(u2[i] & 0xffff)) + bf2f((u16)(u3[i] & 0xffff))) * inv;
    float hi = (bf2f((u16)(u0[i] >> 16))    + bf2f((u16)(u1[i] >> 16)) +
                bf2f((u16)(u2[i] >> 16))    + bf2f((u16)(u3[i] >> 16)))    * inv;
    wp[i] = (unsigned)f2bf(lo) | ((unsigned)f2bf(hi) << 16);
  }
  *(uint4*)(ao + e8*8) = w;
}

// ---------------- proj GEMM + bias + residual: out[b][o][n] = x + W*ao + b ----------------
__global__ __launch_bounds__(256) void proj_gemm_k(const u16* __restrict__ ao, const u16* __restrict__ wp,
        const float* __restrict__ pb, const float* __restrict__ x, float* __restrict__ out){
  int n0 = blockIdx.x*128;       // pixel tile
  int m0 = blockIdx.y*128;       // channel tile (0 or 128)
  int b  = blockIdx.z;
  __shared__ u16 smem[10240];
  u16* As = smem;                // proj_w rows [128][LDA]
  u16* Bs = smem + 5120;         // ao rows    [128][LDA]
  int t = threadIdx.x, lane = t & 63, wave = t >> 6;
  int wm = wave >> 1, wn = wave & 1;
  int c15 = lane & 15, g = lane >> 4;
  f32x4 acc[4][4];
  for (int mt = 0; mt < 4; ++mt) for (int nt = 0; nt < 4; ++nt) acc[mt][nt] = (f32x4){0.f,0.f,0.f,0.f};
  const u16* abase = wp + (size_t)m0*256;
  const u16* bbase = ao + ((size_t)b*4096 + n0)*256;
  for (int kk = 0; kk < 8; ++kk){
    int k0 = kk*32;
    for (int it = 0; it < 2; ++it){
      int idx = it*256 + t;
      int row = idx >> 2, ch = idx & 3;
      uint4 va = *(const uint4*)(abase + (size_t)row*256 + k0 + ch*8);
      *(uint4*)(As + row*LDA + ch*8) = va;
      uint4 vb = *(const uint4*)(bbase + (size_t)row*256 + k0 + ch*8);
      *(uint4*)(Bs + row*LDA + ch*8) = vb;
    }
    __syncthreads();
    short8 af[4], bfr[4];
    for (int mt = 0; mt < 4; ++mt) af[mt]  = *(const short8*)(As + (wm*64 + mt*16 + c15)*LDA + g*8);
    for (int nt = 0; nt < 4; ++nt) bfr[nt] = *(const short8*)(Bs + (wn*64 + nt*16 + c15)*LDA + g*8);
    for (int mt = 0; mt < 4; ++mt)
      for (int nt = 0; nt < 4; ++nt)
        acc[mt][nt] = __builtin_amdgcn_mfma_f32_16x16x32_bf16(af[mt], bfr[nt], acc[mt][nt], 0, 0, 0);
    __syncthreads();
  }
  for (int mt = 0; mt < 4; ++mt){
    for (int r = 0; r < 4; ++r){
      int o = m0 + wm*64 + mt*16 + g*4 + r;
      float bias = pb[o];
      for (int nt = 0; nt < 4; ++nt){
        int n = n0 + wn*64 + nt*16 + c15;
        size_t off = ((size_t)b*256 + o)*4096 + n;
        out[off] = x[off] + bias + acc[mt][nt][r];
      }
    }
  }
}

extern "C" void kernel_launch(void* const* d_in, const int* in_sizes, int n_in,
                              void* d_out, int out_size, void* d_ws, size_t ws_size,
                              hipStream_t stream){
  (void)in_sizes; (void)n_in; (void)out_size; (void)ws_size;
  const float* x     = (const float*)d_in[0];
  const float* gw    = (const float*)d_in[1];
  const float* gb    = (const float*)d_in[2];
  const float* qkvw  = (const float*)d_in[3];
  const float* qkvb  = (const float*)d_in[4];
  const float* projw = (const float*)d_in[5];
  const float* projb = (const float*)d_in[6];
  float* out = (float*)d_out;
  char* ws = (char*)d_ws;

  u16*   xn    = (u16*)(ws + XN_OFF);
  u16*   op    = (u16*)(ws + OP_OFF);
  u16*   ao    = (u16*)(ws + OP_OFF);   // aliases opart split 0 (safe: combine reads-before-write per thread)
  u16*   qws   = (u16*)(ws + QW_OFF);
  u16*   kws   = (u16*)(ws + KW_OFF);
  u16*   vws   = (u16*)(ws + VW_OFF);
  float* lp    = (float*)(ws + LP_OFF);
  u16*   wqb   = (u16*)(ws + WQB_OFF);
  u16*   wpb   = (u16*)(ws + WPB_OFF);
  float* stats = (float*)(ws + ST_OFF);

  wcvt_k<<<1024, 256, 0, stream>>>(qkvw, projw, wqb, wpb);
  gn_stats_k<<<64, 256, 0, stream>>>(x, stats);
  gn_apply_k<<<dim3(64, 4, 4), 256, 0, stream>>>(x, gw, gb, stats, xn);
  qkv_gemm_k<<<dim3(6, 32, 4), 256, 0, stream>>>(xn, wqb, qkvb, qws, kws, vws);
  flash_k<<<dim3(32, 4, 4), 256, 0, stream>>>(qws, kws, vws, op, lp);
  combine_k<<<2048, 256, 0, stream>>>(op, lp, ao);
  proj_gemm_k<<<dim3(32, 2, 4), 256, 0, stream>>>(ao, wpb, projb, x, out);
}

// Round 4
// 236.518 us; speedup vs baseline: 1.5850x; 1.2878x over previous
//
#include <hip/hip_runtime.h>

// Problem: B=4, C=256, N=H*W=4096, GROUPS=16, qkv: 768x256, proj: 256x256.
// Pipeline: gn_stats -> gn_apply(transpose->bf16) -> qkv GEMM (writes K,V^T in flash's
// swizzled 32-row tile layout) -> flash attention (no-max softmax, KV-split=4, Bc=32,
// double-buffered global_load_lds pipeline, raw barriers + vmcnt(8)) -> combine -> proj (+residual)

typedef unsigned short u16;
typedef __attribute__((ext_vector_type(8))) short short8;   // 8 x bf16 (4 VGPRs)
typedef __attribute__((ext_vector_type(4))) float f32x4;    // MFMA accumulator

// workspace byte offsets (total ~59.5 MB)
#define XN_OFF   0ull            // xn  [4][4096][256] bf16 (8,388,608 B)
#define OP_OFF   0ull            // opart [4][4][4096][256] bf16 overlays xn (33,554,432 B)
#define QW_OFF   33554432ull     // q   [4][4096][256] bf16 (scaled by log2e/16)
#define KW_OFF   41943040ull     // k   tiled-swizzled [4][128 tiles][16KB] (8,388,608 B)
#define VW_OFF   50331648ull     // v^T tiled-swizzled [4][128 tiles][16KB] (8,388,608 B)
#define LP_OFF   58720256ull     // lpart [4][4][4096] f32 (262,144 B)
#define WQB_OFF  58982400ull     // qkv_w bf16 (393,216 B)
#define WPB_OFF  59375616ull     // proj_w bf16 (131,072 B)
#define ST_OFF   59506688ull     // stats [64][2] f32

__device__ __forceinline__ u16 f2bf(float x){
  unsigned u = __float_as_uint(x);
  u += 0x7fffu + ((u >> 16) & 1u);          // RNE
  return (u16)(u >> 16);
}
__device__ __forceinline__ float bf2f(u16 h){
  return __uint_as_float(((unsigned)h) << 16);
}

// ---------------- GroupNorm stats ----------------
__global__ __launch_bounds__(256) void gn_stats_k(const float* __restrict__ x, float* __restrict__ stats){
  int bg = blockIdx.x;
  const float* base = x + (size_t)bg * 65536;
  float s = 0.f, ss = 0.f;
  for (int i = threadIdx.x; i < 16384; i += 256){
    float4 v = ((const float4*)base)[i];
    s  += (v.x + v.y) + (v.z + v.w);
    ss += (v.x*v.x + v.y*v.y) + (v.z*v.z + v.w*v.w);
  }
  for (int off = 32; off; off >>= 1){ s += __shfl_down(s, off, 64); ss += __shfl_down(ss, off, 64); }
  __shared__ float red[8];
  int wave = threadIdx.x >> 6, lane = threadIdx.x & 63;
  if (lane == 0){ red[wave] = s; red[4 + wave] = ss; }
  __syncthreads();
  if (threadIdx.x == 0){
    float S  = red[0] + red[1] + red[2] + red[3];
    float SS = red[4] + red[5] + red[6] + red[7];
    float mu = S * (1.f/65536.f);
    float var = SS * (1.f/65536.f) - mu*mu;
    stats[bg*2]   = mu;
    stats[bg*2+1] = rsqrtf(var + 1e-5f);
  }
}

// ---------------- GN apply + transpose ----------------
__global__ __launch_bounds__(256) void gn_apply_k(const float* __restrict__ x, const float* __restrict__ gw,
                                                  const float* __restrict__ gb, const float* __restrict__ stats,
                                                  u16* __restrict__ xn){
  int b = blockIdx.z, c0 = blockIdx.y*64, n0 = blockIdx.x*64;
  __shared__ float tile[64*65];
  int t = threadIdx.x;
  for (int i = 0; i < 16; ++i){
    int idx = i*256 + t;
    int cl = idx >> 6, nl = idx & 63;
    int c = c0 + cl;
    float mu = stats[(b*16 + (c>>4))*2];
    float rs = stats[(b*16 + (c>>4))*2 + 1];
    float v = x[((size_t)b*256 + c)*4096 + n0 + nl];
    tile[cl*65 + nl] = (v - mu)*rs*gw[c] + gb[c];
  }
  __syncthreads();
  for (int i = 0; i < 16; ++i){
    int idx = i*256 + t;
    int nl = idx >> 6, cl = idx & 63;
    xn[((size_t)b*4096 + n0 + nl)*256 + c0 + cl] = f2bf(tile[cl*65 + nl]);
  }
}

// ---------------- weight f32 -> bf16 ----------------
__global__ __launch_bounds__(256) void wcvt_k(const float* __restrict__ wq, const float* __restrict__ wp,
                                              u16* __restrict__ wqb, u16* __restrict__ wpb){
  int i = blockIdx.x*256 + threadIdx.x;
  if (i < 196608) wqb[i] = f2bf(wq[i]);
  else            wpb[i - 196608] = f2bf(wp[i - 196608]);
}

// ---------------- qkv GEMM ----------------
#define LDA 40
#define QSCALE 0.09016844f   // log2(e)/16
__global__ __launch_bounds__(256) void qkv_gemm_k(const u16* __restrict__ xn, const u16* __restrict__ wq,
        const float* __restrict__ qb, u16* __restrict__ q, u16* __restrict__ k, u16* __restrict__ v){
  int bx = blockIdx.x;           // 0-1:q, 2-3:k, 4-5:v
  int m0 = blockIdx.y*128;
  int b  = blockIdx.z;
  __shared__ u16 smem[16384];
  u16* As = smem;
  u16* Bs = smem + 5120;
  int t = threadIdx.x, lane = t & 63, wave = t >> 6;
  int wm = wave >> 1, wn = wave & 1;
  int c15 = lane & 15, g = lane >> 4;
  f32x4 acc[4][4];
  for (int mt = 0; mt < 4; ++mt) for (int nt = 0; nt < 4; ++nt) acc[mt][nt] = (f32x4){0.f,0.f,0.f,0.f};
  const u16* abase = xn + ((size_t)b*4096 + m0)*256;
  const u16* bbase = wq + (size_t)bx*128*256;
  for (int kk = 0; kk < 8; ++kk){
    int k0 = kk*32;
    for (int it = 0; it < 2; ++it){
      int idx = it*256 + t;
      int row = idx >> 2, ch = idx & 3;
      uint4 va = *(const uint4*)(abase + (size_t)row*256 + k0 + ch*8);
      *(uint4*)(As + row*LDA + ch*8) = va;
      uint4 vb = *(const uint4*)(bbase + (size_t)row*256 + k0 + ch*8);
      *(uint4*)(Bs + row*LDA + ch*8) = vb;
    }
    __syncthreads();
    short8 af[4], bfr[4];
    for (int mt = 0; mt < 4; ++mt) af[mt]  = *(const short8*)(As + (wm*64 + mt*16 + c15)*LDA + g*8);
    for (int nt = 0; nt < 4; ++nt) bfr[nt] = *(const short8*)(Bs + (wn*64 + nt*16 + c15)*LDA + g*8);
    for (int mt = 0; mt < 4; ++mt)
      for (int nt = 0; nt < 4; ++nt)
        acc[mt][nt] = __builtin_amdgcn_mfma_f32_16x16x32_bf16(af[mt], bfr[nt], acc[mt][nt], 0, 0, 0);
    __syncthreads();
  }
  if (bx < 2){
    // q: linear [b][n][c], scaled by QSCALE
    for (int nt = 0; nt < 4; ++nt){
      int col = bx*128 + wn*64 + nt*16 + c15;
      float bias = qb[col];
      for (int mt = 0; mt < 4; ++mt){
        int m = m0 + wm*64 + mt*16 + g*4;
        for (int r = 0; r < 4; ++r){
          float val = (acc[mt][nt][r] + bias) * QSCALE;
          q[((size_t)b*4096 + m + r)*256 + col] = f2bf(val);
        }
      }
    }
  } else if (bx < 4){
    // k: swizzled 32-row tiles; element (n,c) at tile n>>5, addr below (matches flash kf reads)
    for (int nt = 0; nt < 4; ++nt){
      int col = bx*128 + wn*64 + nt*16 + c15;
      int c = col - 256;
      float bias = qb[col];
      for (int mt = 0; mt < 4; ++mt){
        int m = m0 + wm*64 + mt*16 + g*4;
        for (int r = 0; r < 4; ++r){
          int n = m + r;
          float val = acc[mt][nt][r] + bias;
          size_t addr = ((size_t)b*128 + (n >> 5))*8192 +
                        (size_t)((n & 31)*256 + (((c >> 3) ^ (n & 7)) << 3) + (c & 7));
          k[addr] = f2bf(val);
        }
      }
    }
  } else {
    // v: transpose via LDS, then store v^T in swizzled 32-col tiles (matches flash vf reads)
    __syncthreads();
    char* Tb = (char*)smem;
    for (int nt = 0; nt < 4; ++nt){
      int o_l = wn*64 + nt*16 + c15;
      float bias = qb[bx*128 + o_l];
      for (int mt = 0; mt < 4; ++mt){
        int mb = wm*64 + mt*16 + g*4;
        unsigned p0 = (unsigned)f2bf(acc[mt][nt][0] + bias) | ((unsigned)f2bf(acc[mt][nt][1] + bias) << 16);
        unsigned p1 = (unsigned)f2bf(acc[mt][nt][2] + bias) | ((unsigned)f2bf(acc[mt][nt][3] + bias) << 16);
        int base = o_l*256 + (((mb >> 3) ^ (o_l & 7)) << 4) + ((mb & 7) << 1);
        *(unsigned*)(Tb + base)     = p0;
        *(unsigned*)(Tb + base + 4) = p1;
      }
    }
    __syncthreads();
    for (int it = 0; it < 8; ++it){
      int idx = it*256 + t;
      int ro = idx >> 4, ch = idx & 15;
      uint4 val = *(const uint4*)(Tb + ro*256 + ((ch ^ (ro & 7)) << 4));
      int c = bx*128 - 512 + ro;            // absolute channel 0..255
      int n = m0 + ch*8;                    // aligned 8-col chunk
      size_t addr = ((size_t)b*128 + (n >> 5))*8192 +
                    (size_t)(c*32 + ((((n >> 3) & 3) ^ ((c >> 1) & 3)) << 3));
      *(uint4*)(v + addr) = val;
    }
  }
}

// ---------------- flash attention: Bc=32, double-buffered DMA pipeline ----------------
// waitcnt imms: vmcnt(8)=0x0F78, vmcnt(0)=0x0F70, lgkmcnt(0)=0xC07F
__global__ __launch_bounds__(256, 2) void flash_k(const u16* __restrict__ q, const u16* __restrict__ kt,
                                                  const u16* __restrict__ vt, u16* __restrict__ opart,
                                                  float* __restrict__ lpart){
  int n0 = blockIdx.x*128;
  int jh = blockIdx.y;
  int b  = blockIdx.z;
  __shared__ u16 buf[2][16384];   // 2 x 32KB: [K tile 16KB][V^T tile 16KB]
  int t = threadIdx.x, lane = t & 63, wave = t >> 6;
  int c15 = lane & 15, g = lane >> 4;

  // Q B-frags for two 16-row i-tiles, resident in registers
  uint4 qf[2][8];
  for (int it2 = 0; it2 < 2; ++it2){
    const u16* qrow = q + ((size_t)b*4096 + n0 + wave*32 + it2*16 + c15)*256;
    for (int kb = 0; kb < 8; ++kb) qf[it2][kb] = *(const uint4*)(qrow + kb*32 + g*8);
  }

  f32x4 oacc[2][16];
  for (int it2 = 0; it2 < 2; ++it2)
    for (int ct = 0; ct < 16; ++ct) oacc[it2][ct] = (f32x4){0.f,0.f,0.f,0.f};
  float lsum[2] = {0.f, 0.f};

  size_t tb0 = ((size_t)b*128 + jh*32) * 16384;   // byte offset of this split's first tile
  const char* gK = (const char*)kt + tb0;
  const char* gV = (const char*)vt + tb0;
  const char* gsrc = (wave < 2) ? (gK + wave*8192) : (gV + (wave - 2)*8192);
  unsigned lds_off = wave*8192;  // byte offset within buf[p] (waves 2,3 land in V half)

  // prime tiles 0 and 1
  {
    const char* g0 = gsrc + (size_t)lane*16;
    #pragma unroll
    for (int i = 0; i < 8; ++i)
      __builtin_amdgcn_global_load_lds((const __attribute__((address_space(1))) void*)(g0 + i*1024),
          (__attribute__((address_space(3))) void*)((char*)buf[0] + lds_off + i*1024), 16, 0, 0);
    const char* g1 = gsrc + 16384 + (size_t)lane*16;
    #pragma unroll
    for (int i = 0; i < 8; ++i)
      __builtin_amdgcn_global_load_lds((const __attribute__((address_space(1))) void*)(g1 + i*1024),
          (__attribute__((address_space(3))) void*)((char*)buf[1] + lds_off + i*1024), 16, 0, 0);
  }

  for (int jt = 0; jt < 32; ++jt){
    int p = jt & 1;
    asm volatile("" ::: "memory");
    if (jt < 31) __builtin_amdgcn_s_waitcnt(0x0F78);   // vmcnt(8): tile jt landed, jt+1 may fly
    else         __builtin_amdgcn_s_waitcnt(0x0F70);   // vmcnt(0)
    __builtin_amdgcn_s_barrier();
    asm volatile("" ::: "memory");

    const u16* klds = buf[p];
    const u16* vlds = buf[p] + 8192;

    // S^T = K * Q^T : lane holds S^T[j=16*tt+4g+r][i=c15]
    f32x4 sacc[2][2];
    sacc[0][0] = (f32x4){0.f,0.f,0.f,0.f}; sacc[0][1] = (f32x4){0.f,0.f,0.f,0.f};
    sacc[1][0] = (f32x4){0.f,0.f,0.f,0.f}; sacc[1][1] = (f32x4){0.f,0.f,0.f,0.f};
    #pragma unroll
    for (int kb = 0; kb < 8; ++kb){
      #pragma unroll
      for (int tt = 0; tt < 2; ++tt){
        int j = tt*16 + c15;
        short8 kf = *(const short8*)(klds + j*256 + (((kb*4 + g) ^ (j & 7)) << 3));
        sacc[0][tt] = __builtin_amdgcn_mfma_f32_16x16x32_bf16(kf, *(const short8*)&qf[0][kb], sacc[0][tt], 0, 0, 0);
        sacc[1][tt] = __builtin_amdgcn_mfma_f32_16x16x32_bf16(kf, *(const short8*)&qf[1][kb], sacc[1][tt], 0, 0, 0);
      }
    }
    // no-max softmax numerator + butterfly to A-operand layout
    uint4 pfr[2];
    #pragma unroll
    for (int it2 = 0; it2 < 2; ++it2){
      unsigned pkv[4];
      #pragma unroll
      for (int tt = 0; tt < 2; ++tt){
        float p0 = exp2f(sacc[it2][tt][0]);
        float p1 = exp2f(sacc[it2][tt][1]);
        float p2 = exp2f(sacc[it2][tt][2]);
        float p3 = exp2f(sacc[it2][tt][3]);
        lsum[it2] += (p0 + p1) + (p2 + p3);
        pkv[tt*2]   = (unsigned)f2bf(p0) | ((unsigned)f2bf(p1) << 16);
        pkv[tt*2+1] = (unsigned)f2bf(p2) | ((unsigned)f2bf(p3) << 16);
      }
      uint4 fr; unsigned* frp = (unsigned*)&fr;
      #pragma unroll
      for (int qd = 0; qd < 4; ++qd){
        int src = c15 + 16*(2*(g & 1) + (qd >> 1));
        unsigned a   = (unsigned)__shfl((int)pkv[qd & 1],       src, 64);
        unsigned bsh = (unsigned)__shfl((int)pkv[2 + (qd & 1)], src, 64);
        frp[qd] = (g >> 1) ? bsh : a;
      }
      pfr[it2] = fr;
    }
    // O += P*V (V-frag reused across both i-tiles)
    #pragma unroll
    for (int ct = 0; ct < 16; ++ct){
      int c = ct*16 + c15;
      short8 vf = *(const short8*)(vlds + c*32 + ((g ^ ((c >> 1) & 3)) << 3));
      oacc[0][ct] = __builtin_amdgcn_mfma_f32_16x16x32_bf16(*(const short8*)&pfr[0], vf, oacc[0][ct], 0, 0, 0);
      oacc[1][ct] = __builtin_amdgcn_mfma_f32_16x16x32_bf16(*(const short8*)&pfr[1], vf, oacc[1][ct], 0, 0, 0);
    }

    asm volatile("" ::: "memory");
    __builtin_amdgcn_s_waitcnt(0xC07F);     // lgkmcnt(0): my LDS reads retired
    __builtin_amdgcn_s_barrier();           // all waves done reading buf[p]
    asm volatile("" ::: "memory");
    if (jt + 2 < 32){
      const char* gn = gsrc + (size_t)(jt + 2)*16384 + (size_t)lane*16;
      #pragma unroll
      for (int i = 0; i < 8; ++i)
        __builtin_amdgcn_global_load_lds((const __attribute__((address_space(1))) void*)(gn + i*1024),
            (__attribute__((address_space(3))) void*)((char*)buf[p] + lds_off + i*1024), 16, 0, 0);
    }
  }

  // epilogue: reduce l across the 4 lane-groups of each row, store partials
  for (int it2 = 0; it2 < 2; ++it2){
    float tot = lsum[it2];
    tot += __shfl_xor(tot, 16, 64);
    tot += __shfl_xor(tot, 32, 64);
    int row = n0 + wave*32 + it2*16;
    if (g == 0) lpart[(size_t)(jh*4 + b)*4096 + row + c15] = tot;
    u16* obase = opart + ((size_t)(jh*4 + b)*4096 + row)*256;
    for (int ct = 0; ct < 16; ++ct)
      for (int r = 0; r < 4; ++r)
        obase[(size_t)(g*4 + r)*256 + ct*16 + c15] = f2bf(oacc[it2][ct][r]);
  }
}

// ---------------- combine KV-split partials -> ao (aliases opart split 0) ----------------
__global__ __launch_bounds__(256) void combine_k(const u16* __restrict__ opart, const float* __restrict__ lpart,
                                                 u16* __restrict__ ao){
  size_t e8 = (size_t)blockIdx.x*256 + threadIdx.x;
  size_t row = e8 >> 5;
  uint4 o0 = *(const uint4*)(opart + e8*8);
  uint4 o1 = *(const uint4*)(opart + 4194304ull  + e8*8);
  uint4 o2 = *(const uint4*)(opart + 8388608ull  + e8*8);
  uint4 o3 = *(const uint4*)(opart + 12582912ull + e8*8);
  float inv = 1.0f / (lpart[row] + lpart[16384 + row] + lpart[32768 + row] + lpart[49152 + row]);
  const unsigned* u0 = (const unsigned*)&o0;
  const unsigned* u1 = (const unsigned*)&o1;
  const unsigned* u2 = (const unsigned*)&o2;
  const unsigned* u3 = (const unsigned*)&o3;
  uint4 w;
  unsigned* wp = (unsigned*)&w;
  for (int i = 0; i < 4; ++i){
    float lo = (bf2f((u16)(u0[i] & 0xffff)) + bf2f((u16)(u1[i] & 0xffff)) +
                bf2f((u16)(u2[i] & 0xffff)) + bf2f((u16)(u3[i] & 0xffff))) * inv;
    float hi = (bf2f((u16)(u0[i] >> 16))    + bf2f((u16)(u1[i] >> 16)) +
                bf2f((u16)(u2[i] >> 16))    + bf2f((u16)(u3[i] >> 16)))    * inv;
    wp[i] = (unsigned)f2bf(lo) | ((unsigned)f2bf(hi) << 16);
  }
  *(uint4*)(ao + e8*8) = w;
}

// ---------------- proj GEMM + bias + residual ----------------
__global__ __launch_bounds__(256) void proj_gemm_k(const u16* __restrict__ ao, const u16* __restrict__ wp,
        const float* __restrict__ pb, const float* __restrict__ x, float* __restrict__ out){
  int n0 = blockIdx.x*128;
  int m0 = blockIdx.y*128;
  int b  = blockIdx.z;
  __shared__ u16 smem[10240];
  u16* As = smem;
  u16* Bs = smem + 5120;
  int t = threadIdx.x, lane = t & 63, wave = t >> 6;
  int wm = wave >> 1, wn = wave & 1;
  int c15 = lane & 15, g = lane >> 4;
  f32x4 acc[4][4];
  for (int mt = 0; mt < 4; ++mt) for (int nt = 0; nt < 4; ++nt) acc[mt][nt] = (f32x4){0.f,0.f,0.f,0.f};
  const u16* abase = wp + (size_t)m0*256;
  const u16* bbase = ao + ((size_t)b*4096 + n0)*256;
  for (int kk = 0; kk < 8; ++kk){
    int k0 = kk*32;
    for (int it = 0; it < 2; ++it){
      int idx = it*256 + t;
      int row = idx >> 2, ch = idx & 3;
      uint4 va = *(const uint4*)(abase + (size_t)row*256 + k0 + ch*8);
      *(uint4*)(As + row*LDA + ch*8) = va;
      uint4 vb = *(const uint4*)(bbase + (size_t)row*256 + k0 + ch*8);
      *(uint4*)(Bs + row*LDA + ch*8) = vb;
    }
    __syncthreads();
    short8 af[4], bfr[4];
    for (int mt = 0; mt < 4; ++mt) af[mt]  = *(const short8*)(As + (wm*64 + mt*16 + c15)*LDA + g*8);
    for (int nt = 0; nt < 4; ++nt) bfr[nt] = *(const short8*)(Bs + (wn*64 + nt*16 + c15)*LDA + g*8);
    for (int mt = 0; mt < 4; ++mt)
      for (int nt = 0; nt < 4; ++nt)
        acc[mt][nt] = __builtin_amdgcn_mfma_f32_16x16x32_bf16(af[mt], bfr[nt], acc[mt][nt], 0, 0, 0);
    __syncthreads();
  }
  for (int mt = 0; mt < 4; ++mt){
    for (int r = 0; r < 4; ++r){
      int o = m0 + wm*64 + mt*16 + g*4 + r;
      float bias = pb[o];
      for (int nt = 0; nt < 4; ++nt){
        int n = n0 + wn*64 + nt*16 + c15;
        size_t off = ((size_t)b*256 + o)*4096 + n;
        out[off] = x[off] + bias + acc[mt][nt][r];
      }
    }
  }
}

extern "C" void kernel_launch(void* const* d_in, const int* in_sizes, int n_in,
                              void* d_out, int out_size, void* d_ws, size_t ws_size,
                              hipStream_t stream){
  (void)in_sizes; (void)n_in; (void)out_size; (void)ws_size;
  const float* x     = (const float*)d_in[0];
  const float* gw    = (const float*)d_in[1];
  const float* gb    = (const float*)d_in[2];
  const float* qkvw  = (const float*)d_in[3];
  const float* qkvb  = (const float*)d_in[4];
  const float* projw = (const float*)d_in[5];
  const float* projb = (const float*)d_in[6];
  float* out = (float*)d_out;
  char* ws = (char*)d_ws;

  u16*   xn    = (u16*)(ws + XN_OFF);
  u16*   op    = (u16*)(ws + OP_OFF);
  u16*   ao    = (u16*)(ws + OP_OFF);   // aliases opart split 0 (combine reads-before-write per thread)
  u16*   qws   = (u16*)(ws + QW_OFF);
  u16*   kws   = (u16*)(ws + KW_OFF);
  u16*   vws   = (u16*)(ws + VW_OFF);
  float* lp    = (float*)(ws + LP_OFF);
  u16*   wqb   = (u16*)(ws + WQB_OFF);
  u16*   wpb   = (u16*)(ws + WPB_OFF);
  float* stats = (float*)(ws + ST_OFF);

  wcvt_k<<<1024, 256, 0, stream>>>(qkvw, projw, wqb, wpb);
  gn_stats_k<<<64, 256, 0, stream>>>(x, stats);
  gn_apply_k<<<dim3(64, 4, 4), 256, 0, stream>>>(x, gw, gb, stats, xn);
  qkv_gemm_k<<<dim3(6, 32, 4), 256, 0, stream>>>(xn, wqb, qkvb, qws, kws, vws);
  flash_k<<<dim3(32, 4, 4), 256, 0, stream>>>(qws, kws, vws, op, lp);
  combine_k<<<2048, 256, 0, stream>>>(op, lp, ao);
  proj_gemm_k<<<dim3(32, 2, 4), 256, 0, stream>>>(ao, wpb, projb, x, out);
}

// Round 5
// 221.937 us; speedup vs baseline: 1.6891x; 1.0657x over previous
//
#include <hip/hip_runtime.h>

// Problem: B=4, C=256, N=H*W=4096, GROUPS=16, qkv: 768x256, proj: 256x256.
// Pipeline: gn_part(512 blocks) -> gn_apply(finalize stats + transpose->bf16) -> qkv GEMM (BK=64;
// writes K,V^T in flash's swizzled 32-row tile layout) -> flash attention (32x32x16 MFMA, no-max
// softmax, KV-split=4, Bc=32, double-buffered global_load_lds pipeline) -> combine -> proj (+residual)

typedef unsigned short u16;
typedef __attribute__((ext_vector_type(8)))  short short8;   // 8 x bf16 (4 VGPRs)
typedef __attribute__((ext_vector_type(4)))  float f32x4;
typedef __attribute__((ext_vector_type(16))) float f32x16;   // 32x32 MFMA accumulator

// workspace byte offsets (total ~59.5 MB)
#define XN_OFF   0ull            // xn  [4][4096][256] bf16 (8,388,608 B)
#define OP_OFF   0ull            // opart [4][4][4096][256] bf16 overlays xn (33,554,432 B)
#define QW_OFF   33554432ull     // q [4][4096][256] bf16 (scaled log2e/16); pstats overlays pre-qkv
#define KW_OFF   41943040ull     // k   tiled-swizzled [4][128 tiles][16KB] (8,388,608 B)
#define VW_OFF   50331648ull     // v^T tiled-swizzled [4][128 tiles][16KB] (8,388,608 B)
#define LP_OFF   58720256ull     // lpart [4][4][4096] f32 (262,144 B)
#define WQB_OFF  58982400ull     // qkv_w bf16 (393,216 B)
#define WPB_OFF  59375616ull     // proj_w bf16 (131,072 B)

__device__ __forceinline__ u16 f2bf(float x){
  unsigned u = __float_as_uint(x);
  u += 0x7fffu + ((u >> 16) & 1u);          // RNE
  return (u16)(u >> 16);
}
__device__ __forceinline__ float bf2f(u16 h){
  return __uint_as_float(((unsigned)h) << 16);
}

// ---------------- GroupNorm partial sums: 512 blocks (64 bg x 8 slices) ----------------
__global__ __launch_bounds__(256) void gn_part_k(const float* __restrict__ x, float* __restrict__ pstats){
  int bg = blockIdx.y, sl = blockIdx.x;
  const float* base = x + (size_t)bg*65536 + (size_t)sl*8192;
  float s = 0.f, ss = 0.f;
  for (int i = threadIdx.x; i < 2048; i += 256){
    float4 v = ((const float4*)base)[i];
    s  += (v.x + v.y) + (v.z + v.w);
    ss += (v.x*v.x + v.y*v.y) + (v.z*v.z + v.w*v.w);
  }
  for (int off = 32; off; off >>= 1){ s += __shfl_down(s, off, 64); ss += __shfl_down(ss, off, 64); }
  __shared__ float red[8];
  int wave = threadIdx.x >> 6, lane = threadIdx.x & 63;
  if (lane == 0){ red[wave] = s; red[4 + wave] = ss; }
  __syncthreads();
  if (threadIdx.x == 0){
    pstats[(bg*8 + sl)*2]     = red[0] + red[1] + red[2] + red[3];
    pstats[(bg*8 + sl)*2 + 1] = red[4] + red[5] + red[6] + red[7];
  }
}

// ---------------- GN finalize + apply + transpose: x[b][c][n] f32 -> xn[b][n][c] bf16 ----------------
__global__ __launch_bounds__(256) void gn_apply_k(const float* __restrict__ x, const float* __restrict__ gw,
                                                  const float* __restrict__ gb, const float* __restrict__ pstats,
                                                  u16* __restrict__ xn){
  int b = blockIdx.z, c0 = blockIdx.y*64, n0 = blockIdx.x*64;
  __shared__ float tile[64*65];
  __shared__ float gmu[4], grs[4];
  int t = threadIdx.x;
  if (t < 4){
    int gidx = (b*16 + (c0 >> 4) + t)*8;
    float S = 0.f, SS = 0.f;
    for (int k2 = 0; k2 < 8; ++k2){ S += pstats[(gidx + k2)*2]; SS += pstats[(gidx + k2)*2 + 1]; }
    float mu = S*(1.f/65536.f);
    gmu[t] = mu;
    grs[t] = rsqrtf(SS*(1.f/65536.f) - mu*mu + 1e-5f);
  }
  __syncthreads();
  for (int i = 0; i < 16; ++i){
    int idx = i*256 + t;
    int cl = idx >> 6, nl = idx & 63;
    int c = c0 + cl;
    float v = x[((size_t)b*256 + c)*4096 + n0 + nl];
    tile[cl*65 + nl] = (v - gmu[cl>>4])*grs[cl>>4]*gw[c] + gb[c];
  }
  __syncthreads();
  for (int i = 0; i < 16; ++i){
    int idx = i*256 + t;
    int nl = idx >> 6, cl = idx & 63;
    xn[((size_t)b*4096 + n0 + nl)*256 + c0 + cl] = f2bf(tile[cl*65 + nl]);
  }
}

// ---------------- weight f32 -> bf16 ----------------
__global__ __launch_bounds__(256) void wcvt_k(const float* __restrict__ wq, const float* __restrict__ wp,
                                              u16* __restrict__ wqb, u16* __restrict__ wpb){
  int i = blockIdx.x*256 + threadIdx.x;
  if (i < 196608) wqb[i] = f2bf(wq[i]);
  else            wpb[i - 196608] = f2bf(wp[i - 196608]);
}

// ---------------- qkv GEMM: BK=64 (4 K-chunks, half the barriers) ----------------
#define LDA 40   // proj kernel stride (BK=32)
#define LDB 72   // qkv stride (BK=64)
#define QSCALE 0.09016844f   // log2(e)/16
__global__ __launch_bounds__(256) void qkv_gemm_k(const u16* __restrict__ xn, const u16* __restrict__ wq,
        const float* __restrict__ qb, u16* __restrict__ q, u16* __restrict__ k, u16* __restrict__ v){
  int bx = blockIdx.x;           // 0-1:q, 2-3:k, 4-5:v
  int m0 = blockIdx.y*128;
  int b  = blockIdx.z;
  __shared__ u16 smem[2*128*LDB];   // 36 KB; v-transpose epilogue reuses 32 KB
  u16* As = smem;
  u16* Bs = smem + 128*LDB;
  int t = threadIdx.x, lane = t & 63, wave = t >> 6;
  int wm = wave >> 1, wn = wave & 1;
  int c15 = lane & 15, g = lane >> 4;
  f32x4 acc[4][4];
  for (int mt = 0; mt < 4; ++mt) for (int nt = 0; nt < 4; ++nt) acc[mt][nt] = (f32x4){0.f,0.f,0.f,0.f};
  const u16* abase = xn + ((size_t)b*4096 + m0)*256;
  const u16* bbase = wq + (size_t)bx*128*256;
  for (int kk = 0; kk < 4; ++kk){
    int k0 = kk*64;
    for (int it = 0; it < 4; ++it){
      int idx = it*256 + t;               // 0..1023 -> 128 rows x 8 chunks
      int row = idx >> 3, ch = idx & 7;
      uint4 va = *(const uint4*)(abase + (size_t)row*256 + k0 + ch*8);
      *(uint4*)(As + row*LDB + ch*8) = va;
      uint4 vb = *(const uint4*)(bbase + (size_t)row*256 + k0 + ch*8);
      *(uint4*)(Bs + row*LDB + ch*8) = vb;
    }
    __syncthreads();
    for (int half = 0; half < 2; ++half){
      short8 af[4], bfr[4];
      for (int mt = 0; mt < 4; ++mt) af[mt]  = *(const short8*)(As + (wm*64 + mt*16 + c15)*LDB + half*32 + g*8);
      for (int nt = 0; nt < 4; ++nt) bfr[nt] = *(const short8*)(Bs + (wn*64 + nt*16 + c15)*LDB + half*32 + g*8);
      for (int mt = 0; mt < 4; ++mt)
        for (int nt = 0; nt < 4; ++nt)
          acc[mt][nt] = __builtin_amdgcn_mfma_f32_16x16x32_bf16(af[mt], bfr[nt], acc[mt][nt], 0, 0, 0);
    }
    __syncthreads();
  }
  if (bx < 2){
    for (int nt = 0; nt < 4; ++nt){
      int col = bx*128 + wn*64 + nt*16 + c15;
      float bias = qb[col];
      for (int mt = 0; mt < 4; ++mt){
        int m = m0 + wm*64 + mt*16 + g*4;
        for (int r = 0; r < 4; ++r){
          float val = (acc[mt][nt][r] + bias) * QSCALE;
          q[((size_t)b*4096 + m + r)*256 + col] = f2bf(val);
        }
      }
    }
  } else if (bx < 4){
    // k: swizzled 32-row tiles (matches flash kf reads)
    for (int nt = 0; nt < 4; ++nt){
      int col = bx*128 + wn*64 + nt*16 + c15;
      int c = col - 256;
      float bias = qb[col];
      for (int mt = 0; mt < 4; ++mt){
        int m = m0 + wm*64 + mt*16 + g*4;
        for (int r = 0; r < 4; ++r){
          int n = m + r;
          float val = acc[mt][nt][r] + bias;
          size_t addr = ((size_t)b*128 + (n >> 5))*8192 +
                        (size_t)((n & 31)*256 + (((c >> 3) ^ (n & 7)) << 3) + (c & 7));
          k[addr] = f2bf(val);
        }
      }
    }
  } else {
    // v: transpose via LDS, store v^T in swizzled 32-col tiles (matches flash vf reads)
    __syncthreads();
    char* Tb = (char*)smem;
    for (int nt = 0; nt < 4; ++nt){
      int o_l = wn*64 + nt*16 + c15;
      float bias = qb[bx*128 + o_l];
      for (int mt = 0; mt < 4; ++mt){
        int mb = wm*64 + mt*16 + g*4;
        unsigned p0 = (unsigned)f2bf(acc[mt][nt][0] + bias) | ((unsigned)f2bf(acc[mt][nt][1] + bias) << 16);
        unsigned p1 = (unsigned)f2bf(acc[mt][nt][2] + bias) | ((unsigned)f2bf(acc[mt][nt][3] + bias) << 16);
        int base = o_l*256 + (((mb >> 3) ^ (o_l & 7)) << 4) + ((mb & 7) << 1);
        *(unsigned*)(Tb + base)     = p0;
        *(unsigned*)(Tb + base + 4) = p1;
      }
    }
    __syncthreads();
    for (int it = 0; it < 8; ++it){
      int idx = it*256 + t;
      int ro = idx >> 4, ch = idx & 15;
      uint4 val = *(const uint4*)(Tb + ro*256 + ((ch ^ (ro & 7)) << 4));
      int c = bx*128 - 512 + ro;
      int n = m0 + ch*8;
      size_t addr = ((size_t)b*128 + (n >> 5))*8192 +
                    (size_t)(c*32 + ((((n >> 3) & 3) ^ ((c >> 1) & 3)) << 3));
      *(uint4*)(v + addr) = val;
    }
  }
}

// ---------------- flash attention: 32x32x16 MFMA, Bc=32, double-buffered DMA pipeline ----------------
// waitcnt imms: vmcnt(8)=0x0F78, vmcnt(0)=0x0F70, lgkmcnt(0)=0xC07F
__global__ __launch_bounds__(256, 2) void flash_k(const u16* __restrict__ q, const u16* __restrict__ kt,
                                                  const u16* __restrict__ vt, u16* __restrict__ opart,
                                                  float* __restrict__ lpart){
  int n0 = blockIdx.x*128;
  int jh = blockIdx.y;
  int b  = blockIdx.z;
  __shared__ u16 buf[2][16384];   // 2 x 32KB: [K tile 16KB][V^T tile 16KB]
  int t = threadIdx.x, lane = t & 63, wave = t >> 6;
  int il = lane & 31;             // query col / key row / channel col (per matrix)
  int h  = lane >> 5;             // lane half

  // Q B-frags: lane holds Q[i = n0+wave*32+il][ch = 16s+8h .. +7], s=0..15 (64 VGPRs)
  uint4 qf[16];
  const u16* qrow = q + ((size_t)b*4096 + n0 + wave*32 + il)*256;
  #pragma unroll
  for (int s = 0; s < 16; ++s) qf[s] = *(const uint4*)(qrow + s*16 + h*8);

  f32x16 oacc[8];
  #pragma unroll
  for (int ct = 0; ct < 8; ++ct){
    #pragma unroll
    for (int r = 0; r < 16; ++r) oacc[ct][r] = 0.f;
  }
  float lsum = 0.f;

  size_t tb0 = ((size_t)b*128 + jh*32) * 16384;   // byte offset of this split's first tile
  const char* gK = (const char*)kt + tb0;
  const char* gV = (const char*)vt + tb0;
  const char* gsrc = (wave < 2) ? (gK + wave*8192) : (gV + (wave - 2)*8192);
  unsigned lds_off = wave*8192;

  // prime tiles 0 and 1
  {
    const char* g0 = gsrc + (size_t)lane*16;
    #pragma unroll
    for (int i = 0; i < 8; ++i)
      __builtin_amdgcn_global_load_lds((const __attribute__((address_space(1))) void*)(g0 + i*1024),
          (__attribute__((address_space(3))) void*)((char*)buf[0] + lds_off + i*1024), 16, 0, 0);
    const char* g1 = gsrc + 16384 + (size_t)lane*16;
    #pragma unroll
    for (int i = 0; i < 8; ++i)
      __builtin_amdgcn_global_load_lds((const __attribute__((address_space(1))) void*)(g1 + i*1024),
          (__attribute__((address_space(3))) void*)((char*)buf[1] + lds_off + i*1024), 16, 0, 0);
  }

  for (int jt = 0; jt < 32; ++jt){
    int p = jt & 1;
    asm volatile("" ::: "memory");
    if (jt < 31) __builtin_amdgcn_s_waitcnt(0x0F78);   // vmcnt(8)
    else         __builtin_amdgcn_s_waitcnt(0x0F70);   // vmcnt(0)
    __builtin_amdgcn_s_barrier();
    asm volatile("" ::: "memory");

    const u16* klds = buf[p];
    const u16* vlds = buf[p] + 8192;

    // S^T (32 keys x 32 queries) = K * Q^T, two interleaved accumulator chains
    f32x16 s0, s1;
    #pragma unroll
    for (int r = 0; r < 16; ++r){ s0[r] = 0.f; s1[r] = 0.f; }
    #pragma unroll
    for (int s = 0; s < 16; s += 2){
      short8 kf0 = *(const short8*)(klds + il*256 + (((2*s + h)     ^ (il & 7)) << 3));
      short8 kf1 = *(const short8*)(klds + il*256 + (((2*(s+1) + h) ^ (il & 7)) << 3));
      s0 = __builtin_amdgcn_mfma_f32_32x32x16_bf16(kf0, *(const short8*)&qf[s],   s0, 0, 0, 0);
      s1 = __builtin_amdgcn_mfma_f32_32x32x16_bf16(kf1, *(const short8*)&qf[s+1], s1, 0, 0, 0);
    }
    // no-max softmax numerator; D-layout: lane holds S^T[j=(r&3)+8(r>>2)+4h][i=il]
    float pv[16];
    #pragma unroll
    for (int r = 0; r < 16; ++r){
      float e = exp2f(s0[r] + s1[r]);
      pv[r] = e;
      lsum += e;
    }
    // C->A conversion: per K-step s2, exchange half the j-values with lane^32
    uint4 pf[2];
    #pragma unroll
    for (int s2 = 0; s2 < 2; ++s2){
      unsigned u0 = (unsigned)f2bf(pv[8*s2+0]) | ((unsigned)f2bf(pv[8*s2+1]) << 16);
      unsigned u1 = (unsigned)f2bf(pv[8*s2+2]) | ((unsigned)f2bf(pv[8*s2+3]) << 16);
      unsigned u2 = (unsigned)f2bf(pv[8*s2+4]) | ((unsigned)f2bf(pv[8*s2+5]) << 16);
      unsigned u3 = (unsigned)f2bf(pv[8*s2+6]) | ((unsigned)f2bf(pv[8*s2+7]) << 16);
      unsigned e1 = h ? u0 : u2;                      // send what partner needs
      unsigned e2 = h ? u1 : u3;
      unsigned r1 = (unsigned)__shfl_xor((int)e1, 32, 64);
      unsigned r2 = (unsigned)__shfl_xor((int)e2, 32, 64);
      uint4 fr;
      fr.x = h ? r1 : u0;
      fr.y = h ? r2 : u1;
      fr.z = h ? u2 : r1;
      fr.w = h ? u3 : r2;
      pf[s2] = fr;
    }
    // O += P*V : 8 channel tiles x 2 K-steps
    #pragma unroll
    for (int s2 = 0; s2 < 2; ++s2){
      short8 pa = *(const short8*)&pf[s2];
      #pragma unroll
      for (int ct = 0; ct < 8; ++ct){
        int c = ct*32 + il;
        short8 vf = *(const short8*)(vlds + c*32 + (((2*s2 + h) ^ ((c >> 1) & 3)) << 3));
        oacc[ct] = __builtin_amdgcn_mfma_f32_32x32x16_bf16(pa, vf, oacc[ct], 0, 0, 0);
      }
    }

    asm volatile("" ::: "memory");
    __builtin_amdgcn_s_waitcnt(0xC07F);     // lgkmcnt(0): my LDS reads retired
    __builtin_amdgcn_s_barrier();           // all waves done reading buf[p]
    asm volatile("" ::: "memory");
    if (jt + 2 < 32){
      const char* gn = gsrc + (size_t)(jt + 2)*16384 + (size_t)lane*16;
      #pragma unroll
      for (int i = 0; i < 8; ++i)
        __builtin_amdgcn_global_load_lds((const __attribute__((address_space(1))) void*)(gn + i*1024),
            (__attribute__((address_space(3))) void*)((char*)buf[p] + lds_off + i*1024), 16, 0, 0);
    }
  }

  // epilogue: l-sum across lane halves, store partials
  float tot = lsum + __shfl_xor(lsum, 32, 64);
  if (h == 0) lpart[(size_t)(jh*4 + b)*4096 + n0 + wave*32 + il] = tot;
  u16* obase = opart + ((size_t)(jh*4 + b)*4096 + n0 + wave*32)*256;
  #pragma unroll
  for (int ct = 0; ct < 8; ++ct){
    #pragma unroll
    for (int r = 0; r < 16; ++r){
      int i = (r & 3) + 8*(r >> 2) + 4*h;
      obase[(size_t)i*256 + ct*32 + il] = f2bf(oacc[ct][r]);
    }
  }
}

// ---------------- combine KV-split partials -> ao (aliases opart split 0) ----------------
__global__ __launch_bounds__(256) void combine_k(const u16* __restrict__ opart, const float* __restrict__ lpart,
                                                 u16* __restrict__ ao){
  size_t e8 = (size_t)blockIdx.x*256 + threadIdx.x;
  size_t row = e8 >> 5;
  uint4 o0 = *(const uint4*)(opart + e8*8);
  uint4 o1 = *(const uint4*)(opart + 4194304ull  + e8*8);
  uint4 o2 = *(const uint4*)(opart + 8388608ull  + e8*8);
  uint4 o3 = *(const uint4*)(opart + 12582912ull + e8*8);
  float inv = 1.0f / (lpart[row] + lpart[16384 + row] + lpart[32768 + row] + lpart[49152 + row]);
  const unsigned* u0 = (const unsigned*)&o0;
  const unsigned* u1 = (const unsigned*)&o1;
  const unsigned* u2 = (const unsigned*)&o2;
  const unsigned* u3 = (const unsigned*)&o3;
  uint4 w;
  unsigned* wp = (unsigned*)&w;
  for (int i = 0; i < 4; ++i){
    float lo = (bf2f((u16)(u0[i] & 0xffff)) + bf2f((u16)(u1[i] & 0xffff)) +
                bf2f((u16)(u2[i] & 0xffff)) + bf2f((u16)(u3[i] & 0xffff))) * inv;
    float hi = (bf2f((u16)(u0[i] >> 16))    + bf2f((u16)(u1[i] >> 16)) +
                bf2f((u16)(u2[i] >> 16))    + bf2f((u16)(u3[i] >> 16)))    * inv;
    wp[i] = (unsigned)f2bf(lo) | ((unsigned)f2bf(hi) << 16);
  }
  *(uint4*)(ao + e8*8) = w;
}

// ---------------- proj GEMM + bias + residual ----------------
__global__ __launch_bounds__(256) void proj_gemm_k(const u16* __restrict__ ao, const u16* __restrict__ wp,
        const float* __restrict__ pb, const float* __restrict__ x, float* __restrict__ out){
  int n0 = blockIdx.x*128;
  int m0 = blockIdx.y*128;
  int b  = blockIdx.z;
  __shared__ u16 smem[10240];
  u16* As = smem;
  u16* Bs = smem + 5120;
  int t = threadIdx.x, lane = t & 63, wave = t >> 6;
  int wm = wave >> 1, wn = wave & 1;
  int c15 = lane & 15, g = lane >> 4;
  f32x4 acc[4][4];
  for (int mt = 0; mt < 4; ++mt) for (int nt = 0; nt < 4; ++nt) acc[mt][nt] = (f32x4){0.f,0.f,0.f,0.f};
  const u16* abase = wp + (size_t)m0*256;
  const u16* bbase = ao + ((size_t)b*4096 + n0)*256;
  for (int kk = 0; kk < 8; ++kk){
    int k0 = kk*32;
    for (int it = 0; it < 2; ++it){
      int idx = it*256 + t;
      int row = idx >> 2, ch = idx & 3;
      uint4 va = *(const uint4*)(abase + (size_t)row*256 + k0 + ch*8);
      *(uint4*)(As + row*LDA + ch*8) = va;
      uint4 vb = *(const uint4*)(bbase + (size_t)row*256 + k0 + ch*8);
      *(uint4*)(Bs + row*LDA + ch*8) = vb;
    }
    __syncthreads();
    short8 af[4], bfr[4];
    for (int mt = 0; mt < 4; ++mt) af[mt]  = *(const short8*)(As + (wm*64 + mt*16 + c15)*LDA + g*8);
    for (int nt = 0; nt < 4; ++nt) bfr[nt] = *(const short8*)(Bs + (wn*64 + nt*16 + c15)*LDA + g*8);
    for (int mt = 0; mt < 4; ++mt)
      for (int nt = 0; nt < 4; ++nt)
        acc[mt][nt] = __builtin_amdgcn_mfma_f32_16x16x32_bf16(af[mt], bfr[nt], acc[mt][nt], 0, 0, 0);
    __syncthreads();
  }
  for (int mt = 0; mt < 4; ++mt){
    for (int r = 0; r < 4; ++r){
      int o = m0 + wm*64 + mt*16 + g*4 + r;
      float bias = pb[o];
      for (int nt = 0; nt < 4; ++nt){
        int n = n0 + wn*64 + nt*16 + c15;
        size_t off = ((size_t)b*256 + o)*4096 + n;
        out[off] = x[off] + bias + acc[mt][nt][r];
      }
    }
  }
}

extern "C" void kernel_launch(void* const* d_in, const int* in_sizes, int n_in,
                              void* d_out, int out_size, void* d_ws, size_t ws_size,
                              hipStream_t stream){
  (void)in_sizes; (void)n_in; (void)out_size; (void)ws_size;
  const float* x     = (const float*)d_in[0];
  const float* gw    = (const float*)d_in[1];
  const float* gb    = (const float*)d_in[2];
  const float* qkvw  = (const float*)d_in[3];
  const float* qkvb  = (const float*)d_in[4];
  const float* projw = (const float*)d_in[5];
  const float* projb = (const float*)d_in[6];
  float* out = (float*)d_out;
  char* ws = (char*)d_ws;

  u16*   xn    = (u16*)(ws + XN_OFF);
  u16*   op    = (u16*)(ws + OP_OFF);
  u16*   ao    = (u16*)(ws + OP_OFF);     // aliases opart split 0 (combine reads-before-write)
  u16*   qws   = (u16*)(ws + QW_OFF);
  float* pstat = (float*)(ws + QW_OFF);   // pstats overlays q region; consumed before qkv writes q
  u16*   kws   = (u16*)(ws + KW_OFF);
  u16*   vws   = (u16*)(ws + VW_OFF);
  float* lp    = (float*)(ws + LP_OFF);
  u16*   wqb   = (u16*)(ws + WQB_OFF);
  u16*   wpb   = (u16*)(ws + WPB_OFF);

  wcvt_k<<<1024, 256, 0, stream>>>(qkvw, projw, wqb, wpb);
  gn_part_k<<<dim3(8, 64), 256, 0, stream>>>(x, pstat);
  gn_apply_k<<<dim3(64, 4, 4), 256, 0, stream>>>(x, gw, gb, pstat, xn);
  qkv_gemm_k<<<dim3(6, 32, 4), 256, 0, stream>>>(xn, wqb, qkvb, qws, kws, vws);
  flash_k<<<dim3(32, 4, 4), 256, 0, stream>>>(qws, kws, vws, op, lp);
  combine_k<<<2048, 256, 0, stream>>>(op, lp, ao);
  proj_gemm_k<<<dim3(32, 2, 4), 256, 0, stream>>>(ao, wpb, projb, x, out);
}

// Round 6
// 174.523 us; speedup vs baseline: 2.1480x; 1.2717x over previous
//
#include <hip/hip_runtime.h>

// Problem: B=4, C=256, N=H*W=4096, GROUPS=16, qkv: 768x256, proj: 256x256.
// Pipeline: gnw (gn partial stats + weight cvt) -> gn_apply -> qkv GEMM (bf16 core, fp8 q/k/v
// epilogues in flash's swizzled layouts) -> flash attention (fp8 32x32x16 MFMA, no-max softmax,
// KV-split=4, Bc=32, double-buffered global_load_lds) -> proj GEMM (fused KV-split combine + residual)

typedef unsigned short u16;
typedef unsigned char  u8;
typedef __attribute__((ext_vector_type(8)))  short short8;
typedef __attribute__((ext_vector_type(4)))  float f32x4;
typedef __attribute__((ext_vector_type(16))) float f32x16;

// workspace byte offsets (~47 MB)
#define XN_OFF   0ull            // xn  [4][4096][256] bf16 (8,388,608 B)
#define OP_OFF   0ull            // opart [4][4][4096][256] bf16 overlays xn (33,554,432 B)
#define QW_OFF   33554432ull     // q fp8 [4][4096][256] (4,194,304 B); pstats overlays pre-qkv
#define KW_OFF   37748736ull     // k fp8 tiled-swizzled [4][128][8KB]
#define VW_OFF   41943040ull     // v^T fp8 tiled-swizzled [4][128][8KB]
#define LP_OFF   46137344ull     // lpart [4][4][4096] f32 (262,144 B)
#define WQB_OFF  46399488ull     // qkv_w bf16 (393,216 B)
#define WPB_OFF  46792704ull     // proj_w bf16 (131,072 B)

#define QSCALE 0.09016844f       // log2(e)/16 (applied to scores inside flash)

__device__ __forceinline__ u16 f2bf(float x){
  unsigned u = __float_as_uint(x);
  u += 0x7fffu + ((u >> 16) & 1u);          // RNE
  return (u16)(u >> 16);
}
__device__ __forceinline__ float bf2f(u16 h){
  return __uint_as_float(((unsigned)h) << 16);
}
__device__ __forceinline__ u8 f2fp8(float x){
  return (u8)(__builtin_amdgcn_cvt_pk_fp8_f32(x, x, 0, false) & 0xff);
}

// ---------------- GN partial stats (512 blocks) + weight f32->bf16 (16 blocks) ----------------
__global__ __launch_bounds__(256) void gnw_k(const float* __restrict__ x, const float* __restrict__ wq,
                                             const float* __restrict__ wp, float* __restrict__ pstats,
                                             u16* __restrict__ wqb, u16* __restrict__ wpb){
  int t = threadIdx.x;
  if (blockIdx.y < 64){
    int bg = blockIdx.y, sl = blockIdx.x;
    const float* base = x + (size_t)bg*65536 + (size_t)sl*8192;
    float s = 0.f, ss = 0.f;
    for (int i = t; i < 2048; i += 256){
      float4 v = ((const float4*)base)[i];
      s  += (v.x + v.y) + (v.z + v.w);
      ss += (v.x*v.x + v.y*v.y) + (v.z*v.z + v.w*v.w);
    }
    for (int off = 32; off; off >>= 1){ s += __shfl_down(s, off, 64); ss += __shfl_down(ss, off, 64); }
    __shared__ float red[8];
    int wave = t >> 6, lane = t & 63;
    if (lane == 0){ red[wave] = s; red[4 + wave] = ss; }
    __syncthreads();
    if (t == 0){
      pstats[(bg*8 + sl)*2]     = red[0] + red[1] + red[2] + red[3];
      pstats[(bg*8 + sl)*2 + 1] = red[4] + red[5] + red[6] + red[7];
    }
  } else {
    int chunk = (blockIdx.y - 64)*8 + blockIdx.x;    // 0..15, 4096 float4 each
    for (int it = 0; it < 16; ++it){
      int i = chunk*4096 + it*256 + t;               // float4 index, 65536 total
      int elem = i*4;
      float4 v = (elem < 196608) ? ((const float4*)wq)[i] : ((const float4*)wp)[i - 49152];
      uint2 w;
      w.x = (unsigned)f2bf(v.x) | ((unsigned)f2bf(v.y) << 16);
      w.y = (unsigned)f2bf(v.z) | ((unsigned)f2bf(v.w) << 16);
      if (elem < 196608) *(uint2*)(wqb + elem)          = w;
      else               *(uint2*)(wpb + elem - 196608) = w;
    }
  }
}

// ---------------- GN finalize + apply + transpose: x[b][c][n] f32 -> xn[b][n][c] bf16 ----------------
__global__ __launch_bounds__(256) void gn_apply_k(const float* __restrict__ x, const float* __restrict__ gw,
                                                  const float* __restrict__ gb, const float* __restrict__ pstats,
                                                  u16* __restrict__ xn){
  int b = blockIdx.z, c0 = blockIdx.y*64, n0 = blockIdx.x*64;
  __shared__ float tile[64*65];
  __shared__ float gmu[4], grs[4];
  int t = threadIdx.x;
  if (t < 4){
    int gidx = (b*16 + (c0 >> 4) + t)*8;
    float S = 0.f, SS = 0.f;
    for (int k2 = 0; k2 < 8; ++k2){ S += pstats[(gidx + k2)*2]; SS += pstats[(gidx + k2)*2 + 1]; }
    float mu = S*(1.f/65536.f);
    gmu[t] = mu;
    grs[t] = rsqrtf(SS*(1.f/65536.f) - mu*mu + 1e-5f);
  }
  __syncthreads();
  for (int i = 0; i < 16; ++i){
    int idx = i*256 + t;
    int cl = idx >> 6, nl = idx & 63;
    int c = c0 + cl;
    float v = x[((size_t)b*256 + c)*4096 + n0 + nl];
    tile[cl*65 + nl] = (v - gmu[cl>>4])*grs[cl>>4]*gw[c] + gb[c];
  }
  __syncthreads();
  for (int i = 0; i < 16; ++i){
    int idx = i*256 + t;
    int nl = idx >> 6, cl = idx & 63;
    xn[((size_t)b*4096 + n0 + nl)*256 + c0 + cl] = f2bf(tile[cl*65 + nl]);
  }
}

// ---------------- qkv GEMM: BK=64 bf16 core; fp8 epilogues ----------------
#define LDA 40   // proj stride (BK=32)
#define LDB 72   // qkv stride (BK=64)
__global__ __launch_bounds__(256) void qkv_gemm_k(const u16* __restrict__ xn, const u16* __restrict__ wq,
        const float* __restrict__ qb, u8* __restrict__ q, u8* __restrict__ k, u8* __restrict__ v){
  int bx = blockIdx.x;           // 0-1:q, 2-3:k, 4-5:v
  int m0 = blockIdx.y*128;
  int b  = blockIdx.z;
  __shared__ u16 smem[2*128*LDB];   // 36 KB; v-transpose epilogue reuses 32 KB
  u16* As = smem;
  u16* Bs = smem + 128*LDB;
  int t = threadIdx.x, lane = t & 63, wave = t >> 6;
  int wm = wave >> 1, wn = wave & 1;
  int c15 = lane & 15, g = lane >> 4;
  f32x4 acc[4][4];
  for (int mt = 0; mt < 4; ++mt) for (int nt = 0; nt < 4; ++nt) acc[mt][nt] = (f32x4){0.f,0.f,0.f,0.f};
  const u16* abase = xn + ((size_t)b*4096 + m0)*256;
  const u16* bbase = wq + (size_t)bx*128*256;
  for (int kk = 0; kk < 4; ++kk){
    int k0 = kk*64;
    for (int it = 0; it < 4; ++it){
      int idx = it*256 + t;
      int row = idx >> 3, ch = idx & 7;
      uint4 va = *(const uint4*)(abase + (size_t)row*256 + k0 + ch*8);
      *(uint4*)(As + row*LDB + ch*8) = va;
      uint4 vb = *(const uint4*)(bbase + (size_t)row*256 + k0 + ch*8);
      *(uint4*)(Bs + row*LDB + ch*8) = vb;
    }
    __syncthreads();
    for (int half = 0; half < 2; ++half){
      short8 af[4], bfr[4];
      for (int mt = 0; mt < 4; ++mt) af[mt]  = *(const short8*)(As + (wm*64 + mt*16 + c15)*LDB + half*32 + g*8);
      for (int nt = 0; nt < 4; ++nt) bfr[nt] = *(const short8*)(Bs + (wn*64 + nt*16 + c15)*LDB + half*32 + g*8);
      for (int mt = 0; mt < 4; ++mt)
        for (int nt = 0; nt < 4; ++nt)
          acc[mt][nt] = __builtin_amdgcn_mfma_f32_16x16x32_bf16(af[mt], bfr[nt], acc[mt][nt], 0, 0, 0);
    }
    __syncthreads();
  }
  if (bx < 2){
    // q: fp8 linear [b][n][256] (unscaled; QSCALE applied in flash)
    for (int nt = 0; nt < 4; ++nt){
      int col = bx*128 + wn*64 + nt*16 + c15;
      float bias = qb[col];
      for (int mt = 0; mt < 4; ++mt){
        int m = m0 + wm*64 + mt*16 + g*4;
        for (int r = 0; r < 4; ++r)
          q[((size_t)b*4096 + m + r)*256 + col] = f2fp8(acc[mt][nt][r] + bias);
      }
    }
  } else if (bx < 4){
    // k: fp8 swizzled 32-row tiles (matches flash kf b64 reads)
    for (int nt = 0; nt < 4; ++nt){
      int col = bx*128 + wn*64 + nt*16 + c15;
      int c = col - 256;
      float bias = qb[col];
      for (int mt = 0; mt < 4; ++mt){
        int m = m0 + wm*64 + mt*16 + g*4;
        for (int r = 0; r < 4; ++r){
          int n = m + r;
          size_t addr = ((size_t)b*128 + (n >> 5))*8192 +
                        (size_t)((n & 31)*256 + (((c >> 3) ^ (n & 15)) << 3) + (c & 7));
          k[addr] = f2fp8(acc[mt][nt][r] + bias);
        }
      }
    }
  } else {
    // v: bf16 LDS transpose, then fp8 swizzled v^T tiles (matches flash vf b64 reads)
    __syncthreads();
    char* Tb = (char*)smem;
    for (int nt = 0; nt < 4; ++nt){
      int o_l = wn*64 + nt*16 + c15;
      float bias = qb[bx*128 + o_l];
      for (int mt = 0; mt < 4; ++mt){
        int mb = wm*64 + mt*16 + g*4;
        unsigned p0 = (unsigned)f2bf(acc[mt][nt][0] + bias) | ((unsigned)f2bf(acc[mt][nt][1] + bias) << 16);
        unsigned p1 = (unsigned)f2bf(acc[mt][nt][2] + bias) | ((unsigned)f2bf(acc[mt][nt][3] + bias) << 16);
        int base = o_l*256 + (((mb >> 3) ^ (o_l & 7)) << 4) + ((mb & 7) << 1);
        *(unsigned*)(Tb + base)     = p0;
        *(unsigned*)(Tb + base + 4) = p1;
      }
    }
    __syncthreads();
    for (int it = 0; it < 8; ++it){
      int idx = it*256 + t;
      int ro = idx >> 4, ch = idx & 15;
      uint4 val = *(const uint4*)(Tb + ro*256 + ((ch ^ (ro & 7)) << 4));
      int c = bx*128 - 512 + ro;          // absolute channel
      int n = m0 + ch*8;                  // aligned 8-key chunk
      float f0 = bf2f((u16)(val.x & 0xffff)), f1 = bf2f((u16)(val.x >> 16));
      float f2 = bf2f((u16)(val.y & 0xffff)), f3 = bf2f((u16)(val.y >> 16));
      float f4 = bf2f((u16)(val.z & 0xffff)), f5 = bf2f((u16)(val.z >> 16));
      float f6 = bf2f((u16)(val.w & 0xffff)), f7 = bf2f((u16)(val.w >> 16));
      int w0 = __builtin_amdgcn_cvt_pk_fp8_f32(f0, f1, 0, false);
      w0     = __builtin_amdgcn_cvt_pk_fp8_f32(f2, f3, w0, true);
      int w1 = __builtin_amdgcn_cvt_pk_fp8_f32(f4, f5, 0, false);
      w1     = __builtin_amdgcn_cvt_pk_fp8_f32(f6, f7, w1, true);
      size_t addr = ((size_t)b*128 + (n >> 5))*8192 +
                    (size_t)(c*32 + ((((n >> 3) & 3) ^ ((c >> 2) & 3)) << 3));
      uint2 wv; wv.x = (unsigned)w0; wv.y = (unsigned)w1;
      *(uint2*)(v + addr) = wv;
    }
  }
}

// ---------------- flash attention: fp8 32x32x16 MFMA, Bc=32, double-buffered DMA ----------------
// waitcnt imms: vmcnt(4)=0x0F74, vmcnt(0)=0x0F70, lgkmcnt(0)=0xC07F
__global__ __launch_bounds__(256, 2) void flash_k(const u8* __restrict__ q, const u8* __restrict__ kt,
                                                  const u8* __restrict__ vt, u16* __restrict__ opart,
                                                  float* __restrict__ lpart){
  int n0 = blockIdx.x*128;
  int jh = blockIdx.y;
  int b  = blockIdx.z;
  __shared__ char buf[2][16384];   // 2 x 16KB: [K tile 8KB][V^T tile 8KB]
  int t = threadIdx.x, lane = t & 63, wave = t >> 6;
  int il = lane & 31;
  int h  = lane >> 5;

  // Q B-frags (fp8): lane holds Q[i=il][ch = 16s + 8h .. +7]
  uint2 qf[16];
  const u8* qrow = q + ((size_t)b*4096 + n0 + wave*32 + il)*256;
  #pragma unroll
  for (int s = 0; s < 16; ++s) qf[s] = *(const uint2*)(qrow + s*16 + h*8);

  f32x16 oacc[8];
  #pragma unroll
  for (int ct = 0; ct < 8; ++ct){
    #pragma unroll
    for (int r = 0; r < 16; ++r) oacc[ct][r] = 0.f;
  }
  float lsum = 0.f;

  size_t tb0 = ((size_t)b*128 + jh*32) * 8192;
  const char* gK = (const char*)kt + tb0;
  const char* gV = (const char*)vt + tb0;
  const char* gsrc = (wave < 2) ? (gK + wave*4096) : (gV + (wave - 2)*4096);
  unsigned lds_off = wave*4096;    // K in [0,8K), V in [8K,16K)

  // prime tiles 0 and 1
  {
    const char* g0 = gsrc + (size_t)lane*16;
    #pragma unroll
    for (int i = 0; i < 4; ++i)
      __builtin_amdgcn_global_load_lds((const __attribute__((address_space(1))) void*)(g0 + i*1024),
          (__attribute__((address_space(3))) void*)((char*)buf[0] + lds_off + i*1024), 16, 0, 0);
    const char* g1 = gsrc + 8192 + (size_t)lane*16;
    #pragma unroll
    for (int i = 0; i < 4; ++i)
      __builtin_amdgcn_global_load_lds((const __attribute__((address_space(1))) void*)(g1 + i*1024),
          (__attribute__((address_space(3))) void*)((char*)buf[1] + lds_off + i*1024), 16, 0, 0);
  }

  for (int jt = 0; jt < 32; ++jt){
    int p = jt & 1;
    asm volatile("" ::: "memory");
    if (jt < 31) __builtin_amdgcn_s_waitcnt(0x0F74);   // vmcnt(4)
    else         __builtin_amdgcn_s_waitcnt(0x0F70);   // vmcnt(0)
    __builtin_amdgcn_s_barrier();
    asm volatile("" ::: "memory");

    const char* klds = buf[p];
    const char* vlds = buf[p] + 8192;

    // S^T (32 keys x 32 queries) = K * Q^T, fp8 K=16 steps, two chains
    f32x16 s0, s1;
    #pragma unroll
    for (int r = 0; r < 16; ++r){ s0[r] = 0.f; s1[r] = 0.f; }
    #pragma unroll
    for (int s = 0; s < 16; s += 2){
      long kf0 = *(const long*)(klds + il*256 + (((2*s + h)       ^ (il & 15)) << 3));
      long kf1 = *(const long*)(klds + il*256 + (((2*(s+1) + h)   ^ (il & 15)) << 3));
      s0 = __builtin_amdgcn_mfma_f32_32x32x16_fp8_fp8(kf0, *(const long*)&qf[s],   s0, 0, 0, 0);
      s1 = __builtin_amdgcn_mfma_f32_32x32x16_fp8_fp8(kf1, *(const long*)&qf[s+1], s1, 0, 0, 0);
    }
    // no-max softmax numerator; D: lane holds S^T[j=(r&3)+8(r>>2)+4h][i=il]
    float pv[16];
    #pragma unroll
    for (int r = 0; r < 16; ++r){
      float e = exp2f((s0[r] + s1[r]) * QSCALE);
      pv[r] = e;
      lsum += e;
    }
    // C->A: pack to fp8, one shfl_xor(32) per K-step
    long pa[2];
    #pragma unroll
    for (int s2 = 0; s2 < 2; ++s2){
      int q0 = __builtin_amdgcn_cvt_pk_fp8_f32(pv[8*s2+0], pv[8*s2+1], 0, false);
      q0     = __builtin_amdgcn_cvt_pk_fp8_f32(pv[8*s2+2], pv[8*s2+3], q0, true);
      int q1 = __builtin_amdgcn_cvt_pk_fp8_f32(pv[8*s2+4], pv[8*s2+5], 0, false);
      q1     = __builtin_amdgcn_cvt_pk_fp8_f32(pv[8*s2+6], pv[8*s2+7], q1, true);
      int e  = h ? q0 : q1;
      int rr = __shfl_xor(e, 32, 64);
      unsigned lo = (unsigned)(h ? rr : q0);
      unsigned hi = (unsigned)(h ? q1 : rr);
      pa[s2] = ((long)hi << 32) | (long)lo;
    }
    // O += P*V
    #pragma unroll
    for (int s2 = 0; s2 < 2; ++s2){
      #pragma unroll
      for (int ct = 0; ct < 8; ++ct){
        int c = ct*32 + il;
        long vf = *(const long*)(vlds + c*32 + (((2*s2 + h) ^ ((c >> 2) & 3)) << 3));
        oacc[ct] = __builtin_amdgcn_mfma_f32_32x32x16_fp8_fp8(pa[s2], vf, oacc[ct], 0, 0, 0);
      }
    }

    asm volatile("" ::: "memory");
    __builtin_amdgcn_s_waitcnt(0xC07F);     // lgkmcnt(0)
    __builtin_amdgcn_s_barrier();
    asm volatile("" ::: "memory");
    if (jt + 2 < 32){
      const char* gn2 = gsrc + (size_t)(jt + 2)*8192 + (size_t)lane*16;
      #pragma unroll
      for (int i = 0; i < 4; ++i)
        __builtin_amdgcn_global_load_lds((const __attribute__((address_space(1))) void*)(gn2 + i*1024),
            (__attribute__((address_space(3))) void*)((char*)buf[p] + lds_off + i*1024), 16, 0, 0);
    }
  }

  // epilogue
  float tot = lsum + __shfl_xor(lsum, 32, 64);
  if (h == 0) lpart[(size_t)(jh*4 + b)*4096 + n0 + wave*32 + il] = tot;
  u16* obase = opart + ((size_t)(jh*4 + b)*4096 + n0 + wave*32)*256;
  #pragma unroll
  for (int ct = 0; ct < 8; ++ct){
    #pragma unroll
    for (int r = 0; r < 16; ++r){
      int i = (r & 3) + 8*(r >> 2) + 4*h;
      obase[(size_t)i*256 + ct*32 + il] = f2bf(oacc[ct][r]);
    }
  }
}

// ---------------- proj GEMM with fused KV-split combine + bias + residual ----------------
// out[b][o][n] = x + pb[o] + sum_c W[o][c] * (sum_s opart[s][b][n][c]) / (sum_s lpart[s][b][n])
__global__ __launch_bounds__(256) void proj_gemm_k(const u16* __restrict__ opart, const float* __restrict__ lpart,
        const u16* __restrict__ wp, const float* __restrict__ pb, const float* __restrict__ x,
        float* __restrict__ out){
  int n0 = blockIdx.x*64;
  int b  = blockIdx.y;
  __shared__ u16 As[256*LDA];    // proj_w chunk 256 x 32
  __shared__ u16 Bs[64*LDA];     // combined ao chunk 64 x 32
  __shared__ float linv[64];
  int t = threadIdx.x, lane = t & 63, wave = t >> 6;
  int c15 = lane & 15, g = lane >> 4;
  if (t < 64){
    size_t row = (size_t)b*4096 + n0 + t;
    linv[t] = 1.0f / (lpart[row] + lpart[16384 + row] + lpart[32768 + row] + lpart[49152 + row]);
  }
  f32x4 acc[4][4];
  for (int mt = 0; mt < 4; ++mt) for (int nt = 0; nt < 4; ++nt) acc[mt][nt] = (f32x4){0.f,0.f,0.f,0.f};
  __syncthreads();
  for (int kk = 0; kk < 8; ++kk){
    int k0 = kk*32;
    for (int it = 0; it < 4; ++it){
      int idx = it*256 + t;
      int row = idx >> 2, ch = idx & 3;
      *(uint4*)(As + row*LDA + ch*8) = *(const uint4*)(wp + (size_t)row*256 + k0 + ch*8);
    }
    {
      int row = t >> 2, ch = t & 3;
      const u16* bptr = opart + ((size_t)b*4096 + n0 + row)*256 + k0 + ch*8;
      uint4 o0 = *(const uint4*)(bptr);
      uint4 o1 = *(const uint4*)(bptr + 4194304ull);
      uint4 o2 = *(const uint4*)(bptr + 8388608ull);
      uint4 o3 = *(const uint4*)(bptr + 12582912ull);
      float inv = linv[row];
      const unsigned* u0 = (const unsigned*)&o0;
      const unsigned* u1 = (const unsigned*)&o1;
      const unsigned* u2 = (const unsigned*)&o2;
      const unsigned* u3 = (const unsigned*)&o3;
      uint4 w;
      unsigned* wpk = (unsigned*)&w;
      for (int i = 0; i < 4; ++i){
        float lo = (bf2f((u16)(u0[i] & 0xffff)) + bf2f((u16)(u1[i] & 0xffff)) +
                    bf2f((u16)(u2[i] & 0xffff)) + bf2f((u16)(u3[i] & 0xffff))) * inv;
        float hi = (bf2f((u16)(u0[i] >> 16))    + bf2f((u16)(u1[i] >> 16)) +
                    bf2f((u16)(u2[i] >> 16))    + bf2f((u16)(u3[i] >> 16)))    * inv;
        wpk[i] = (unsigned)f2bf(lo) | ((unsigned)f2bf(hi) << 16);
      }
      *(uint4*)(Bs + row*LDA + ch*8) = w;
    }
    __syncthreads();
    short8 af[4], bfr[4];
    for (int mt = 0; mt < 4; ++mt) af[mt]  = *(const short8*)(As + (wave*64 + mt*16 + c15)*LDA + g*8);
    for (int nt = 0; nt < 4; ++nt) bfr[nt] = *(const short8*)(Bs + (nt*16 + c15)*LDA + g*8);
    for (int mt = 0; mt < 4; ++mt)
      for (int nt = 0; nt < 4; ++nt)
        acc[mt][nt] = __builtin_amdgcn_mfma_f32_16x16x32_bf16(af[mt], bfr[nt], acc[mt][nt], 0, 0, 0);
    __syncthreads();
  }
  for (int mt = 0; mt < 4; ++mt){
    for (int r = 0; r < 4; ++r){
      int o = wave*64 + mt*16 + g*4 + r;
      float bias = pb[o];
      for (int nt = 0; nt < 4; ++nt){
        int n = n0 + nt*16 + c15;
        size_t off = ((size_t)b*256 + o)*4096 + n;
        out[off] = x[off] + bias + acc[mt][nt][r];
      }
    }
  }
}

extern "C" void kernel_launch(void* const* d_in, const int* in_sizes, int n_in,
                              void* d_out, int out_size, void* d_ws, size_t ws_size,
                              hipStream_t stream){
  (void)in_sizes; (void)n_in; (void)out_size; (void)ws_size;
  const float* x     = (const float*)d_in[0];
  const float* gw    = (const float*)d_in[1];
  const float* gb    = (const float*)d_in[2];
  const float* qkvw  = (const float*)d_in[3];
  const float* qkvb  = (const float*)d_in[4];
  const float* projw = (const float*)d_in[5];
  const float* projb = (const float*)d_in[6];
  float* out = (float*)d_out;
  char* ws = (char*)d_ws;

  u16*   xn    = (u16*)(ws + XN_OFF);
  u16*   op    = (u16*)(ws + OP_OFF);     // overlays xn (xn dead after qkv)
  u8*    qws   = (u8*)(ws + QW_OFF);
  float* pstat = (float*)(ws + QW_OFF);   // overlays q region; consumed before qkv writes q
  u8*    kws   = (u8*)(ws + KW_OFF);
  u8*    vws   = (u8*)(ws + VW_OFF);
  float* lp    = (float*)(ws + LP_OFF);
  u16*   wqb   = (u16*)(ws + WQB_OFF);
  u16*   wpb   = (u16*)(ws + WPB_OFF);

  gnw_k<<<dim3(8, 66), 256, 0, stream>>>(x, qkvw, projw, pstat, wqb, wpb);
  gn_apply_k<<<dim3(64, 4, 4), 256, 0, stream>>>(x, gw, gb, pstat, xn);
  qkv_gemm_k<<<dim3(6, 32, 4), 256, 0, stream>>>(xn, wqb, qkvb, qws, kws, vws);
  flash_k<<<dim3(32, 4, 4), 256, 0, stream>>>(qws, kws, vws, op, lp);
  proj_gemm_k<<<dim3(64, 4), 256, 0, stream>>>(op, lp, wpb, projb, x, out);
}